// Round 10
// baseline (418.741 us; speedup 1.0000x reference)
//
#include <hip/hip_runtime.h>

#define N_NODES 10000
#define N_EDGES 160000
#define HD 512
#define EDD 16

typedef unsigned short u16;
typedef __attribute__((ext_vector_type(8))) short bf16x8;
typedef __attribute__((ext_vector_type(4))) float f32x4;
typedef unsigned int u32;

__device__ __forceinline__ float bf2f(u16 u){
  unsigned int x = ((unsigned int)u) << 16;
  return __builtin_bit_cast(float, x);
}
__device__ __forceinline__ u16 f2bf(float f){
  unsigned int x = __builtin_bit_cast(unsigned int, f);
  unsigned int r = (x + 0x7fffu + ((x >> 16) & 1u)) >> 16;
  return (u16)r;
}
// dtype-flagged scalar load/store: flag!=0 -> f32, else bf16
__device__ __forceinline__ float ldx(const void* p, long long i, int f32){
  return f32 ? ((const float*)p)[i] : bf2f(((const u16*)p)[i]);
}
__device__ __forceinline__ void stx(void* p, long long i, int f32, float v){
  if (f32) ((float*)p)[i] = v; else ((u16*)p)[i] = f2bf(v);
}
// tanh-form gelu, NaN-free sigmoid form: x * rcp(1 + e^{-a})
__device__ __forceinline__ float gelu_f(float x){
  float c = x * x;
  float a = x * (1.5957691216f + 0.0713548162f * c);
  float e = __expf(-a);
  return x * __builtin_amdgcn_rcpf(1.0f + e);
}
__device__ __forceinline__ f32x4 mfma16(bf16x8 a, bf16x8 b, f32x4 c){
  return __builtin_amdgcn_mfma_f32_16x16x32_bf16(a, b, c, 0, 0, 0);
}
// LDS slot swizzle for [row][32]-u16 tiles (4 x 16B slots per row)
__device__ __forceinline__ int swz8(int row, int slot){
  return (slot ^ ((row >> 1) & 3)) * 8;
}
// load 8 contiguous elems as bf16x8 from f32-or-bf16 source (8-elem aligned)
__device__ __forceinline__ bf16x8 ld8(const void* p, long long i, int f32){
  if (!f32) return *(const bf16x8*)((const u16*)p + i);
  const float* q = (const float*)p + i;
  float4 a = *(const float4*)q, b = *(const float4*)(q + 4);
  u16 t[8] = { f2bf(a.x), f2bf(a.y), f2bf(a.z), f2bf(a.w),
               f2bf(b.x), f2bf(b.y), f2bf(b.z), f2bf(b.w) };
  return *(const bf16x8*)t;
}
__device__ __forceinline__ void stage8(const void* src, long long idx, int f32, u16* dst){
  bf16x8 v = ld8(src, idx, f32);
  *(bf16x8*)dst = v;
}

// ---------------- dtype probe
__device__ __forceinline__ int probe_rand(const void* p, int l){
  const u16* q = (const u16*)p;
  float mx = 0.f;
  #pragma unroll
  for (int i = 0; i < 4; ++i) mx = fmaxf(mx, fabsf(bf2f(q[l * 4 + i])));
  #pragma unroll
  for (int m = 1; m < 64; m <<= 1) mx = fmaxf(mx, __shfl_xor(mx, m, 64));
  return (mx > 1e3f) ? 1 : 0;
}
// F[0]=h F[1]=ea F[2]=msg_w1 F[3]=msg_w2 F[4]=upd_w1 F[5]=upd_w2
// F[6]=em_w1 F[7]=em_w2 F[8]=eg_w F[9]=norm_g F[10]=en_g F[11]=out(=h)
__global__ __launch_bounds__(64) void kprobe(
    const void* h, const void* ea, const void* mw1, const void* mw2,
    const void* uw1, const void* uw2, const void* ew1, const void* ew2,
    const void* egw, const void* ng, const void* eng, int* F)
{
  const int l = threadIdx.x;
  int f0 = probe_rand(h, l),   f1 = probe_rand(ea, l),  f2 = probe_rand(mw1, l);
  int f3 = probe_rand(mw2, l), f4 = probe_rand(uw1, l), f5 = probe_rand(uw2, l);
  int f6 = probe_rand(ew1, l), f7 = probe_rand(ew2, l), f8 = probe_rand(egw, l);
  if (l == 0){
    F[0] = f0; F[1] = f1; F[2] = f2; F[3] = f3; F[4] = f4; F[5] = f5;
    F[6] = f6; F[7] = f7; F[8] = f8;
    F[9]  = (((const u16*)ng)[0]  == 0) ? 1 : 0;
    F[10] = (((const u16*)eng)[0] == 0) ? 1 : 0;
    F[11] = f0;
  }
}

__global__ void kfill(u16* __restrict__ out, long long n, float val){
  long long i = (long long)blockIdx.x * 256 + threadIdx.x;
  if (i < n) out[i] = f2bf(val);
}

// ---------------- fused prep #1, grid 2684:
// [0,2500): hB convert  [2500,2572): W1T 64x64 LDS-tiled transpose
// [2572,2668): WceT build  [2668,2684): bfused (j-parallel x8, 32 n/block)
__global__ __launch_bounds__(256) void kprep(
    const void* __restrict__ h, const void* __restrict__ mw1,
    const void* __restrict__ ew1, const void* __restrict__ egw,
    const void* __restrict__ mb2, const void* __restrict__ uw1,
    const int* __restrict__ F,
    u16* __restrict__ hB, u16* __restrict__ W1T, u16* __restrict__ WceT,
    float* __restrict__ bfused)
{
  __shared__ float tl[64][65];
  const int b = blockIdx.x, tid = threadIdx.x;
  if (b < 2500){
    const long long i = ((long long)b * 256 + tid) * 8;
    if (i < (long long)N_NODES * HD)
      *(bf16x8*)(hB + i) = ld8(h, i, F[0]);
  } else if (b < 2572){
    // W1T[n][k] = (k<528) ? msg_w1[k][n] : 0 ; K=528->Kpad 544, N=512
    const int b2 = b - 2500;
    const int kt0 = (b2 >> 3) * 64, nt0 = (b2 & 7) * 64;
    const int ty = tid >> 6, tx = tid & 63;
    const int fw = F[2];
    #pragma unroll
    for (int q = 0; q < 16; ++q){
      const int r = ty * 16 + q;
      const int sr = kt0 + r;
      tl[r][tx] = (sr < 528) ? ldx(mw1, (long long)sr * 512 + nt0 + tx, fw) : 0.f;
    }
    __syncthreads();
    #pragma unroll
    for (int q = 0; q < 16; ++q){
      const int r = ty * 16 + q;
      const int k = kt0 + tx;
      if (k < 544) W1T[(size_t)(nt0 + r) * 544 + k] = f2bf(tl[tx][r]);
    }
  } else if (b < 2668){
    const int i = (b - 2572) * 256 + tid;
    const int c = i >> 9, k = i & 511;
    float v = 0.f;
    if (c < 16)       v = ldx(ew1, (long long)k * 16 + c, F[6]);
    else if (c < 32)  v = ldx(ew1, (long long)(512 + k) * 16 + (c - 16), F[6]);
    else if (c == 32) v = ldx(egw, k, F[8]);
    else if (c == 33) v = ldx(egw, 512 + k, F[8]);
    WceT[i] = f2bf(v);
  } else {
    // bfused[n] = sum_j msg_b2[j]*upd_w1[512+j][n]; 16 blocks x 32 n,
    // 8-way j-parallel per block (64-iter loop, coalesced row slices)
    float* ls   = &tl[0][0];          // 512 floats (b2 staged)
    float* part = &tl[0][0] + 1024;   // 8 x 33 partials
    const int f3 = F[3], f4 = F[4];
    for (int j = tid; j < 512; j += 256) ls[j] = ldx(mb2, j, f3);
    __syncthreads();
    const int nn = tid & 31, jg = tid >> 5;
    const int n = (b - 2668) * 32 + nn;
    float a = 0.f;
    for (int jj = 0; jj < 64; ++jj){
      const int j = jg * 64 + jj;
      a += ls[j] * ldx(uw1, (long long)(512 + j) * 512 + n, f4);
    }
    part[jg * 33 + nn] = a;
    __syncthreads();
    if (jg == 0){
      float s = a;
      #pragma unroll
      for (int g = 1; g < 8; ++g) s += part[g * 33 + nn];
      bfused[n] = s;
    }
  }
}

// ---------------- fused prep #2 (after kedge2 frees PE/WceT), grid 192:
// [0,128): WU1T tiled transpose (1024x512 -> [512][1024])
// [128,192): WU2T tiled transpose (512x512 -> [512][512])
__global__ __launch_bounds__(256) void kprep2(
    const void* __restrict__ uw1, const void* __restrict__ uw2,
    const int* __restrict__ F, u16* __restrict__ WU1T, u16* __restrict__ WU2T)
{
  __shared__ float tl[64][65];
  const int b = blockIdx.x, tid = threadIdx.x;
  const int ty = tid >> 6, tx = tid & 63;
  if (b < 128){
    const int kt0 = (b >> 3) * 64, nt0 = (b & 7) * 64;
    const int fw = F[4];
    #pragma unroll
    for (int q = 0; q < 16; ++q){
      const int r = ty * 16 + q;
      tl[r][tx] = ldx(uw1, (long long)(kt0 + r) * 512 + nt0 + tx, fw);
    }
    __syncthreads();
    #pragma unroll
    for (int q = 0; q < 16; ++q){
      const int r = ty * 16 + q;
      WU1T[(size_t)(nt0 + r) * 1024 + kt0 + tx] = f2bf(tl[tx][r]);
    }
  } else {
    const int b2 = b - 128;
    const int kt0 = (b2 >> 3) * 64, nt0 = (b2 & 7) * 64;
    const int fw = F[5];
    #pragma unroll
    for (int q = 0; q < 16; ++q){
      const int r = ty * 16 + q;
      tl[r][tx] = ldx(uw2, (long long)(kt0 + r) * 512 + nt0 + tx, fw);
    }
    __syncthreads();
    #pragma unroll
    for (int q = 0; q < 16; ++q){
      const int r = ty * 16 + q;
      WU2T[(size_t)(nt0 + r) * 512 + kt0 + tx] = f2bf(tl[tx][r]);
    }
  }
}

__global__ void kdeg(const int* __restrict__ dst, int* __restrict__ deg){
  int e = blockIdx.x * 256 + threadIdx.x;
  if (e < N_EDGES) atomicAdd(&deg[dst[e]], 1);
}

// ---------------- exclusive scan of deg -> start
__global__ __launch_bounds__(256) void kscan(const int* __restrict__ deg,
                                             int* __restrict__ start){
  __shared__ int ls[256];
  const int t = threadIdx.x;
  const int base = t * 40;
  int s = 0;
  for (int i = 0; i < 40; ++i){ int idx = base + i; if (idx < N_NODES) s += deg[idx]; }
  ls[t] = s; __syncthreads();
  for (int off = 1; off < 256; off <<= 1){
    int v = (t >= off) ? ls[t - off] : 0;
    __syncthreads();
    ls[t] += v;
    __syncthreads();
  }
  int run = (t == 0) ? 0 : ls[t - 1];
  for (int i = 0; i < 40; ++i){
    int idx = base + i;
    if (idx < N_NODES){ start[idx] = run; run += deg[idx]; }
  }
}

// ---------------- counting-sort scatter: edges sorted by dst
__global__ void kscatter(const int* __restrict__ srcI, const int* __restrict__ dstI,
                         const int* __restrict__ start, int* __restrict__ cursor,
                         int* __restrict__ sSrc, int* __restrict__ sDst,
                         int* __restrict__ sIdx){
  int e = blockIdx.x * 256 + threadIdx.x;
  if (e < N_EDGES){
    int d = dstI[e];
    int p = start[d] + atomicAdd(&cursor[d], 1);
    sSrc[p] = srcI[e]; sDst[p] = d; sIdx[p] = e;
  }
}

// ---------------- fused: P = bf16(h @ msg_w1[:512] + b1) (x<8, BM128 BN64)
//                  and PE = bf16(h @ WceT^T) [N][48]     (x==8)
// grid (9,79): same-row-panel blocks adjacent in dispatch -> hB L2 reuse
__global__ __launch_bounds__(256, 4) void kprePE(
    const u16* __restrict__ hB, const u16* __restrict__ W1T,
    const void* __restrict__ msg_b1, const u16* __restrict__ WceT,
    const int* __restrict__ F, u16* __restrict__ P, u16* __restrict__ PE)
{
  __shared__ u16 As[128 * 32];
  __shared__ u16 Bs[64 * 32];
  const int tid = threadIdx.x;
  const int row0 = blockIdx.y * 128;
  const int w = tid >> 6, l = tid & 63;
  const int lm = l & 15, lk = l >> 4;
  if (blockIdx.x < 8){
    const int fw = F[2];
    const int n0 = blockIdx.x * 64;
    f32x4 acc[2][4];
    f32x4 z4 = {0.f, 0.f, 0.f, 0.f};
    #pragma unroll
    for (int i = 0; i < 2; ++i)
      #pragma unroll
      for (int j = 0; j < 4; ++j) acc[i][j] = z4;
    const int nB = tid >> 2, kqB = tid & 3;
    for (int kt = 0; kt < 16; ++kt){
      const int kk = kt * 32;
      #pragma unroll
      for (int i = 0; i < 2; ++i){
        int t = tid + i * 256;
        int m = t >> 2, kq = t & 3;
        int gr = row0 + m; if (gr > N_NODES - 1) gr = N_NODES - 1;
        *(uint4*)&As[m * 32 + swz8(m, kq)] = *(const uint4*)(hB + (size_t)gr * HD + kk + kq * 8);
      }
      *(uint4*)&Bs[nB * 32 + swz8(nB, kqB)] =
          *(const uint4*)(W1T + (size_t)(n0 + nB) * 544 + kk + kqB * 8);
      __syncthreads();
      bf16x8 af[2], bfv[4];
      #pragma unroll
      for (int i = 0; i < 2; ++i){
        const int R = w * 32 + i * 16 + lm;
        af[i] = *(const bf16x8*)&As[R * 32 + swz8(R, lk)];
      }
      #pragma unroll
      for (int j = 0; j < 4; ++j){
        const int R = j * 16 + lm;
        bfv[j] = *(const bf16x8*)&Bs[R * 32 + swz8(R, lk)];
      }
      #pragma unroll
      for (int i = 0; i < 2; ++i)
        #pragma unroll
        for (int j = 0; j < 4; ++j)
          acc[i][j] = mfma16(af[i], bfv[j], acc[i][j]);
      __syncthreads();
    }
    #pragma unroll
    for (int j = 0; j < 4; ++j){
      const int col = n0 + j * 16 + lm;
      const float bias = ldx(msg_b1, col, fw);
      #pragma unroll
      for (int i = 0; i < 2; ++i){
        const int rb = row0 + w * 32 + i * 16 + lk * 4;
        #pragma unroll
        for (int r = 0; r < 4; ++r){
          int gr = rb + r;
          if (gr < N_NODES)
            P[(size_t)gr * HD + col] = f2bf(acc[i][j][r] + bias);
        }
      }
    }
  } else {
    f32x4 acc[2][3];
    f32x4 z4 = {0.f, 0.f, 0.f, 0.f};
    #pragma unroll
    for (int i = 0; i < 2; ++i)
      #pragma unroll
      for (int j = 0; j < 3; ++j) acc[i][j] = z4;
    for (int kt = 0; kt < 16; ++kt){
      const int kk = kt * 32;
      #pragma unroll
      for (int i = 0; i < 2; ++i){
        int t = tid + i * 256;
        int m = t >> 2, kq = t & 3;
        int gr = row0 + m; if (gr > N_NODES - 1) gr = N_NODES - 1;
        *(uint4*)&As[m * 32 + swz8(m, kq)] = *(const uint4*)(hB + (size_t)gr * HD + kk + kq * 8);
      }
      if (tid < 192){
        int c = tid >> 2, kq = tid & 3;
        *(uint4*)&Bs[c * 32 + swz8(c, kq)] =
            *(const uint4*)(WceT + (size_t)c * 512 + kk + kq * 8);
      }
      __syncthreads();
      bf16x8 af[2], bfv[3];
      #pragma unroll
      for (int i = 0; i < 2; ++i){
        const int R = w * 32 + i * 16 + lm;
        af[i] = *(const bf16x8*)&As[R * 32 + swz8(R, lk)];
      }
      #pragma unroll
      for (int j = 0; j < 3; ++j){
        const int R = j * 16 + lm;
        bfv[j] = *(const bf16x8*)&Bs[R * 32 + swz8(R, lk)];
      }
      #pragma unroll
      for (int i = 0; i < 2; ++i)
        #pragma unroll
        for (int j = 0; j < 3; ++j)
          acc[i][j] = mfma16(af[i], bfv[j], acc[i][j]);
      __syncthreads();
    }
    #pragma unroll
    for (int j = 0; j < 3; ++j){
      const int col = j * 16 + lm;
      #pragma unroll
      for (int i = 0; i < 2; ++i){
        const int rb = row0 + w * 32 + i * 16 + lk * 4;
        #pragma unroll
        for (int r = 0; r < 4; ++r){
          int gr = rb + r;
          if (gr < N_NODES)
            PE[(size_t)gr * 48 + col] = f2bf(acc[i][j][r]);
        }
      }
    }
  }
}

// ---------------- edge update, decomposed: 1 thread = 1 edge, grid 625
__global__ __launch_bounds__(256) void kedge2(
    const void* __restrict__ ea, const u16* __restrict__ PE,
    const void* __restrict__ em_w1, const void* __restrict__ em_w2,
    const void* __restrict__ em_b1, const void* __restrict__ em_b2,
    const void* __restrict__ eg_w, const void* __restrict__ eg_b,
    const void* __restrict__ en_g, const void* __restrict__ en_b,
    const int* __restrict__ F,
    const int* __restrict__ srcI, const int* __restrict__ dstI,
    void* __restrict__ dout)
{
  __shared__ float wt[16][17];
  __shared__ float w2s[256];
  __shared__ float egt[16], b1e[16], b2s[16], gns[16], bns[16];
  __shared__ float egb_s;
  const int tid = threadIdx.x;
  const int fea = F[1], fem1 = F[6], fem2 = F[7], feg = F[8];
  const int fen = F[10], fo = F[11];
  { int k = tid >> 4, j = tid & 15;
    wt[k][j] = ldx(em_w1, (long long)(1024 + k) * 16 + j, fem1); }
  w2s[tid] = ldx(em_w2, tid, fem2);
  if (tid < 16){
    egt[tid] = ldx(eg_w, 1024 + tid, feg);
    b1e[tid] = ldx(em_b1, tid, fem1);
    b2s[tid] = ldx(em_b2, tid, fem2);
    gns[tid] = ldx(en_g, tid, fen);
    bns[tid] = ldx(en_b, tid, fen);
  }
  if (tid == 0) egb_s = ldx(eg_b, 0, feg);
  __syncthreads();

  const int e = blockIdx.x * 256 + tid;
  const int s = srcI[e], d = dstI[e];
  float earr[16];
  if (fea){
    const float4* q = (const float4*)((const float*)ea + (size_t)e * 16);
    float4 v0 = q[0], v1 = q[1], v2 = q[2], v3 = q[3];
    earr[0]=v0.x; earr[1]=v0.y; earr[2]=v0.z; earr[3]=v0.w;
    earr[4]=v1.x; earr[5]=v1.y; earr[6]=v1.z; earr[7]=v1.w;
    earr[8]=v2.x; earr[9]=v2.y; earr[10]=v2.z; earr[11]=v2.w;
    earr[12]=v3.x; earr[13]=v3.y; earr[14]=v3.z; earr[15]=v3.w;
  } else {
    const u16* q = (const u16*)ea + (size_t)e * 16;
    bf16x8 a = *(const bf16x8*)q, b = *(const bf16x8*)(q + 8);
    #pragma unroll
    for (int j = 0; j < 8; ++j){ earr[j] = bf2f((u16)a[j]); earr[8 + j] = bf2f((u16)b[j]); }
  }
  const u16* prs = PE + (size_t)s * 48;
  const u16* prd = PE + (size_t)d * 48;
  bf16x8 ps0 = *(const bf16x8*)prs,        ps1 = *(const bf16x8*)(prs + 8);
  bf16x8 pd0 = *(const bf16x8*)(prd + 16), pd1 = *(const bf16x8*)(prd + 24);
  const float gs = bf2f(prs[32]), gd = bf2f(prd[33]);
  float t[16];
  #pragma unroll
  for (int j = 0; j < 8; ++j){
    t[j]     = bf2f((u16)ps0[j]) + bf2f((u16)pd0[j]) + b1e[j];
    t[8 + j] = bf2f((u16)ps1[j]) + bf2f((u16)pd1[j]) + b1e[8 + j];
  }
  float gl = gs + gd + egb_s;
  #pragma unroll
  for (int k = 0; k < 16; ++k){
    const float ek = earr[k];
    gl += ek * egt[k];
    #pragma unroll
    for (int j = 0; j < 16; ++j) t[j] += ek * wt[k][j];
  }
  const float gate = __builtin_amdgcn_rcpf(1.0f + __expf(-gl));
  float gj[16];
  #pragma unroll
  for (int j = 0; j < 16; ++j) gj[j] = gelu_f(t[j]);
  float rv[16]; float s1 = 0.f, s2 = 0.f;
  #pragma unroll
  for (int j = 0; j < 16; ++j){
    float dlt = b2s[j];
    #pragma unroll
    for (int k = 0; k < 16; ++k) dlt += gj[k] * w2s[k * 16 + j];
    rv[j] = earr[j] + 0.1f * gate * dlt;
    s1 += rv[j]; s2 += rv[j] * rv[j];
  }
  const float mu  = s1 * (1.f / 16.f);
  const float var = s2 * (1.f / 16.f) - mu * mu;
  const float inv = rsqrtf(var + 1e-5f);
  if (fo){
    float* ob = (float*)dout + (size_t)N_NODES * HD + (size_t)e * 16;
    #pragma unroll
    for (int j = 0; j < 16; ++j) ob[j] = (rv[j] - mu) * inv * gns[j] + bns[j];
  } else {
    u16 tmp[16];
    #pragma unroll
    for (int j = 0; j < 16; ++j) tmp[j] = f2bf((rv[j] - mu) * inv * gns[j] + bns[j]);
    u16* ob = (u16*)dout + (size_t)N_NODES * HD + (size_t)e * 16;
    *(uint4*)ob = *(uint4*)&tmp[0];
    *(uint4*)(ob + 8) = *(uint4*)&tmp[8];
  }
}

// ---------------- WfT[n][k] = sum_j WU1T[n][512+j] * msg_w2[k][j]
// grid (8,4): x=colblock, y=rowblock
__global__ __launch_bounds__(256, 4) void kWf(
    const u16* __restrict__ WU1T, const void* __restrict__ mw2,
    const int* __restrict__ F, u16* __restrict__ WfT)
{
  __shared__ u16 As[128 * 32];
  __shared__ u16 Bs[64 * 32];
  const int tid = threadIdx.x;
  const int f3 = F[3];
  const int row0 = blockIdx.y * 128, n0 = blockIdx.x * 64;
  f32x4 acc[2][4];
  f32x4 z4 = {0.f, 0.f, 0.f, 0.f};
  #pragma unroll
  for (int i = 0; i < 2; ++i)
    #pragma unroll
    for (int j = 0; j < 4; ++j) acc[i][j] = z4;
  const int w = tid >> 6, l = tid & 63;
  const int lm = l & 15, lk = l >> 4;
  const int nB = tid >> 2, kqB = tid & 3;
  for (int kt = 0; kt < 16; ++kt){
    const int kk = kt * 32;
    #pragma unroll
    for (int i = 0; i < 2; ++i){
      int t = tid + i * 256;
      int m = t >> 2, kq = t & 3;
      *(uint4*)&As[m * 32 + swz8(m, kq)] =
          *(const uint4*)(WU1T + (size_t)(row0 + m) * 1024 + 512 + kk + kq * 8);
    }
    stage8(mw2, (long long)(n0 + nB) * 512 + kk + kqB * 8, f3,
           &Bs[nB * 32 + swz8(nB, kqB)]);
    __syncthreads();
    bf16x8 af[2], bfv[4];
    #pragma unroll
    for (int i = 0; i < 2; ++i){
      const int R = w * 32 + i * 16 + lm;
      af[i] = *(const bf16x8*)&As[R * 32 + swz8(R, lk)];
    }
    #pragma unroll
    for (int j = 0; j < 4; ++j){
      const int R = j * 16 + lm;
      bfv[j] = *(const bf16x8*)&Bs[R * 32 + swz8(R, lk)];
    }
    #pragma unroll
    for (int i = 0; i < 2; ++i)
      #pragma unroll
      for (int j = 0; j < 4; ++j)
        acc[i][j] = mfma16(af[i], bfv[j], acc[i][j]);
    __syncthreads();
  }
  #pragma unroll
  for (int j = 0; j < 4; ++j){
    const int col = n0 + j * 16 + lm;
    #pragma unroll
    for (int i = 0; i < 2; ++i){
      const int rb = row0 + w * 32 + i * 16 + lk * 4;
      #pragma unroll
      for (int r = 0; r < 4; ++r)
        WfT[(size_t)(rb + r) * 512 + col] = f2bf(acc[i][j][r]);
    }
  }
}

// ---------------- message via single K=32 MFMA tile + LDS-staged P tile +
// segmented reduce. grid (4,1250): x=colblock, y=edgeblock.
// P tile staged coalesced into Pl[128][132] (conflict-free epilogue reads).
__global__ __launch_bounds__(256, 4) void kmsg5(
    const u16* __restrict__ P, const void* __restrict__ dout,
    const u16* __restrict__ W1T, const int* __restrict__ F,
    const int* __restrict__ sSrc, const int* __restrict__ sDst,
    const int* __restrict__ sIdx,
    float* __restrict__ agg)
{
  __shared__ __align__(16) float SMEM[4352];   // As/Bs (16KB) then Sf (17.4KB)
  __shared__ __align__(16) u16 Pl[128 * 132];  // 33792B P tile
  __shared__ int dst_s[128];
  u16*   As = (u16*)SMEM;
  u16*   Bs = (u16*)SMEM + 4096;
  float* Sf = SMEM;
  const int tid = threadIdx.x;
  const int fo = F[11];
  const void* e_base = fo ? (const void*)((const float*)dout + (size_t)N_NODES * HD)
                          : (const void*)((const u16*)dout + (size_t)N_NODES * HD);
  const int row0 = blockIdx.y * 128, n0 = blockIdx.x * 128;
  if (tid < 128) dst_s[tid] = sDst[row0 + tid];
  // stage As (e_new rows, K=16 real + 16 zeros) and Bs (W1_e cols)
  #pragma unroll
  for (int i = 0; i < 2; ++i){
    int t = tid + i * 256;
    int m = t >> 2, kq = t & 3;
    if (kq < 2){
      const long long ie = sIdx[row0 + m];
      stage8(e_base, ie * EDD + kq * 8, fo, &As[m * 32 + swz8(m, kq)]);
      *(uint4*)&Bs[m * 32 + swz8(m, kq)] =
          *(const uint4*)(W1T + (size_t)(n0 + m) * 544 + 512 + kq * 8);
    } else {
      uint4 z = {0,0,0,0};
      *(uint4*)&As[m * 32 + swz8(m, kq)] = z;
      *(uint4*)&Bs[m * 32 + swz8(m, kq)] = z;
    }
  }
  // stage Pl: 128 rows x 128 cols of P at gathered rows (coalesced 64B segs)
  #pragma unroll
  for (int i = 0; i < 2; ++i){
    int t = tid + i * 256;          // 0..511
    int row = t >> 2, seg = t & 3;  // 4 segs x 32 u16 (64B)
    const uint4* src = (const uint4*)(P + (size_t)sSrc[row0 + row] * HD + n0 + seg * 32);
    uint4 v0 = src[0], v1 = src[1], v2 = src[2], v3 = src[3];
    uint2* d = (uint2*)&Pl[row * 132 + seg * 32];  // 8B-aligned (264B stride)
    d[0] = make_uint2(v0.x, v0.y); d[1] = make_uint2(v0.z, v0.w);
    d[2] = make_uint2(v1.x, v1.y); d[3] = make_uint2(v1.z, v1.w);
    d[4] = make_uint2(v2.x, v2.y); d[5] = make_uint2(v2.z, v2.w);
    d[6] = make_uint2(v3.x, v3.y); d[7] = make_uint2(v3.z, v3.w);
  }
  __syncthreads();
  const int w = tid >> 6, l = tid & 63;
  const int wr = w >> 1, wc = w & 1, lm = l & 15, lk = l >> 4;
  f32x4 acc[4][4];
  bf16x8 af[4], bfv[4];
  #pragma unroll
  for (int i = 0; i < 4; ++i){
    const int R = wr * 64 + i * 16 + lm;
    af[i] = *(const bf16x8*)&As[R * 32 + swz8(R, lk)];
  }
  #pragma unroll
  for (int j = 0; j < 4; ++j){
    const int R = wc * 64 + j * 16 + lm;
    bfv[j] = *(const bf16x8*)&Bs[R * 32 + swz8(R, lk)];
  }
  f32x4 z4 = {0.f, 0.f, 0.f, 0.f};
  #pragma unroll
  for (int i = 0; i < 4; ++i)
    #pragma unroll
    for (int j = 0; j < 4; ++j)
      acc[i][j] = mfma16(af[i], bfv[j], z4);
  // hoist segment structure
  const int cj = tid & 31, chunk = tid >> 5;
  const int rbase = chunk * 16;
  u32 aoff[16]; unsigned maskb = 0;
  {
    int dprev = dst_s[rbase];
    aoff[0] = (u32)dprev * HD;
    #pragma unroll
    for (int rr = 1; rr < 16; ++rr){
      const int dn = dst_s[rbase + rr];
      if (dn == dprev) maskb |= (1u << rr);
      aoff[rr] = (u32)dn * HD;
      dprev = dn;
    }
  }
  __syncthreads();   // all waves done reading As/Bs regs -> Sf may overwrite
  const int sfb = wc * 16 + lm;
  const int plc = wc * 64 + lm;    // P col base within tile (add j*16)
  #pragma unroll
  for (int j = 0; j < 4; ++j){
    #pragma unroll
    for (int i = 0; i < 4; ++i){
      #pragma unroll
      for (int r = 0; r < 4; ++r){
        const int row = wr * 64 + i * 16 + lk * 4 + r;
        const float pv = bf2f(Pl[row * 132 + plc + j * 16]);
        Sf[row * 34 + sfb] = gelu_f(acc[i][j][r] + pv);
      }
    }
    __syncthreads();
    const int acol = n0 + (cj >> 4) * 64 + j * 16 + (cj & 15);
    float run = Sf[rbase * 34 + cj];
    #pragma unroll
    for (int rr = 1; rr < 16; ++rr){
      const float v = Sf[(rbase + rr) * 34 + cj];
      if (maskb & (1u << rr)) run += v;
      else { atomicAdd(&agg[(size_t)aoff[rr - 1] + acol], run); run = v; }
    }
    atomicAdd(&agg[(size_t)aoff[15] + acol], run);
    __syncthreads();
  }
}

// ---------------- U = bf16(gelu(h@W1u_top + S@Wf + deg*bfused + b1u))
// grid (8,79): x=colblock (BN=64), y=rowblock (BM=128), K=1024
__global__ __launch_bounds__(256, 4) void kupd1f(
    const u16* __restrict__ hB, const float* __restrict__ S,
    const u16* __restrict__ WU1T, const u16* __restrict__ WfT,
    const void* __restrict__ upd_b1, const float* __restrict__ bfused,
    const int* __restrict__ deg, const int* __restrict__ F,
    u16* __restrict__ U)
{
  __shared__ u16 As[128 * 32];
  __shared__ u16 Bs[64 * 32];
  const int tid = threadIdx.x;
  const int fw = F[4];
  const int row0 = blockIdx.y * 128, n0 = blockIdx.x * 64;
  f32x4 acc[2][4];
  f32x4 z4 = {0.f, 0.f, 0.f, 0.f};
  #pragma unroll
  for (int i = 0; i < 2; ++i)
    #pragma unroll
    for (int j = 0; j < 4; ++j) acc[i][j] = z4;
  const int w = tid >> 6, l = tid & 63;
  const int lm = l & 15, lk = l >> 4;
  const int nB = tid >> 2, kqB = tid & 3;
  const int am = tid >> 1, ah = tid & 1;
  const int agr = row0 + am;
  for (int kt = 0; kt < 32; ++kt){
    const int kk = kt * 32;
    if (kk < 512){
      #pragma unroll
      for (int i = 0; i < 2; ++i){
        int t = tid + i * 256;
        int m = t >> 2, kq = t & 3;
        int gr = row0 + m; if (gr > N_NODES - 1) gr = N_NODES - 1;
        *(uint4*)&As[m * 32 + swz8(m, kq)] = *(const uint4*)(hB + (size_t)gr * HD + kk + kq * 8);
      }
      *(uint4*)&Bs[nB * 32 + swz8(nB, kqB)] =
          *(const uint4*)(WU1T + (size_t)(n0 + nB) * 1024 + kk + kqB * 8);
    } else {
      const int ks = kk - 512;
      u16 tmp[16];
      if (agr < N_NODES){
        const float4* sp = (const float4*)(S + (size_t)agr * HD + ks + ah * 16);
        #pragma unroll
        for (int q = 0; q < 4; ++q){
          float4 v = sp[q];
          tmp[q*4+0] = f2bf(v.x); tmp[q*4+1] = f2bf(v.y);
          tmp[q*4+2] = f2bf(v.z); tmp[q*4+3] = f2bf(v.w);
        }
      } else {
        #pragma unroll
        for (int q = 0; q < 16; ++q) tmp[q] = 0;
      }
      *(uint4*)&As[am * 32 + swz8(am, ah * 2)]     = *(uint4*)&tmp[0];
      *(uint4*)&As[am * 32 + swz8(am, ah * 2 + 1)] = *(uint4*)&tmp[8];
      *(uint4*)&Bs[nB * 32 + swz8(nB, kqB)] =
          *(const uint4*)(WfT + (size_t)(n0 + nB) * 512 + ks + kqB * 8);
    }
    __syncthreads();
    bf16x8 af[2], bfv[4];
    #pragma unroll
    for (int i = 0; i < 2; ++i){
      const int R = w * 32 + i * 16 + lm;
      af[i] = *(const bf16x8*)&As[R * 32 + swz8(R, lk)];
    }
    #pragma unroll
    for (int j = 0; j < 4; ++j){
      const int R = j * 16 + lm;
      bfv[j] = *(const bf16x8*)&Bs[R * 32 + swz8(R, lk)];
    }
    #pragma unroll
    for (int i = 0; i < 2; ++i)
      #pragma unroll
      for (int j = 0; j < 4; ++j)
        acc[i][j] = mfma16(af[i], bfv[j], acc[i][j]);
    __syncthreads();
  }
  #pragma unroll
  for (int j = 0; j < 4; ++j){
    const int col = n0 + j * 16 + lm;
    const float bias = ldx(upd_b1, col, fw);
    const float bfv2 = bfused[col];
    #pragma unroll
    for (int i = 0; i < 2; ++i){
      const int rb = row0 + w * 32 + i * 16 + lk * 4;
      #pragma unroll
      for (int r = 0; r < 4; ++r){
        int gr = rb + r;
        if (gr < N_NODES)
          U[(size_t)gr * HD + col] =
              f2bf(gelu_f(acc[i][j][r] + bias + (float)deg[gr] * bfv2));
      }
    }
  }
}

// ---------------- h2b = bf16(U @ upd_w2 + b2)   grid (8,79), K=512
__global__ __launch_bounds__(256, 4) void kupd2(
    const u16* __restrict__ U, const u16* __restrict__ WU2T,
    const void* __restrict__ upd_b2, const int* __restrict__ F,
    u16* __restrict__ h2b)
{
  __shared__ u16 As[128 * 32];
  __shared__ u16 Bs[64 * 32];
  const int tid = threadIdx.x;
  const int fw = F[5];
  const int row0 = blockIdx.y * 128, n0 = blockIdx.x * 64;
  f32x4 acc[2][4];
  f32x4 z4 = {0.f, 0.f, 0.f, 0.f};
  #pragma unroll
  for (int i = 0; i < 2; ++i)
    #pragma unroll
    for (int j = 0; j < 4; ++j) acc[i][j] = z4;
  const int w = tid >> 6, l = tid & 63;
  const int lm = l & 15, lk = l >> 4;
  const int nB = tid >> 2, kqB = tid & 3;
  for (int kt = 0; kt < 16; ++kt){
    const int kk = kt * 32;
    #pragma unroll
    for (int i = 0; i < 2; ++i){
      int t = tid + i * 256;
      int m = t >> 2, kq = t & 3;
      int gr = row0 + m; if (gr > N_NODES - 1) gr = N_NODES - 1;
      *(uint4*)&As[m * 32 + swz8(m, kq)] = *(const uint4*)(U + (size_t)gr * HD + kk + kq * 8);
    }
    *(uint4*)&Bs[nB * 32 + swz8(nB, kqB)] =
        *(const uint4*)(WU2T + (size_t)(n0 + nB) * 512 + kk + kqB * 8);
    __syncthreads();
    bf16x8 af[2], bfv[4];
    #pragma unroll
    for (int i = 0; i < 2; ++i){
      const int R = w * 32 + i * 16 + lm;
      af[i] = *(const bf16x8*)&As[R * 32 + swz8(R, lk)];
    }
    #pragma unroll
    for (int j = 0; j < 4; ++j){
      const int R = j * 16 + lm;
      bfv[j] = *(const bf16x8*)&Bs[R * 32 + swz8(R, lk)];
    }
    #pragma unroll
    for (int i = 0; i < 2; ++i)
      #pragma unroll
      for (int j = 0; j < 4; ++j)
        acc[i][j] = mfma16(af[i], bfv[j], acc[i][j]);
    __syncthreads();
  }
  #pragma unroll
  for (int j = 0; j < 4; ++j){
    const int col = n0 + j * 16 + lm;
    const float bias = ldx(upd_b2, col, fw);
    #pragma unroll
    for (int i = 0; i < 2; ++i){
      const int rb = row0 + w * 32 + i * 16 + lk * 4;
      #pragma unroll
      for (int r = 0; r < 4; ++r){
        int gr = rb + r;
        if (gr < N_NODES)
          h2b[(size_t)gr * HD + col] = f2bf(acc[i][j][r] + bias);
      }
    }
  }
}

// ---------------- h_out = LN(h + h2)   grid 2500, 4 rows/block
__global__ __launch_bounds__(256) void kln(
    const void* __restrict__ h, const u16* __restrict__ h2b,
    const void* __restrict__ gg, const void* __restrict__ bbv,
    const int* __restrict__ F, void* __restrict__ dout)
{
  const int fh = F[0], fng = F[9], fo = F[11];
  const int w = threadIdx.x >> 6, l = threadIdx.x & 63;
  const int row = blockIdx.x * 4 + w;
  float x[8];
  #pragma unroll
  for (int j = 0; j < 8; ++j){
    const long long idx = (long long)row * HD + l * 8 + j;
    x[j] = ldx(h, idx, fh) + bf2f(h2b[idx]);
  }
  float s1 = 0.f, s2 = 0.f;
  #pragma unroll
  for (int j = 0; j < 8; ++j){ s1 += x[j]; s2 += x[j] * x[j]; }
  #pragma unroll
  for (int m = 1; m < 64; m <<= 1){ s1 += __shfl_xor(s1, m, 64); s2 += __shfl_xor(s2, m, 64); }
  const float mu  = s1 * (1.f / 512.f);
  const float var = s2 * (1.f / 512.f) - mu * mu;
  const float inv = rsqrtf(var + 1e-5f);
  #pragma unroll
  for (int j = 0; j < 8; ++j){
    const float gf = ldx(gg,  l * 8 + j, fng);
    const float bf = ldx(bbv, l * 8 + j, fng);
    stx(dout, (long long)row * HD + l * 8 + j, fo, (x[j] - mu) * inv * gf + bf);
  }
}

// ---------------- workspace layout (bytes), total 35,448,064 (unchanged)
#define OFF_S     0u            // N*512 f32 (scatter accum; later h2b bf16)
#define OFF_DEG   20480000u     // N ints
#define OFF_CUR   20520000u     // N ints (sort cursors)
#define OFF_F     20560000u     // 16 ints
#define OFF_START 20560064u     // N ints
#define OFF_AGGM  20600064u     // N*512 bf16 (P, then U)
#define OFF_W1T   30840064u     // 512*544 bf16
#define OFF_W2T   31397120u     // 512*512 bf16 (WfT)
#define OFF_WU1T  31921408u     // 512*1024 bf16 (PE first)
#define OFF_WU2T  32969984u     // 512*512 bf16 (WceT first)
#define OFF_WET   33494272u     // bfused (512 f32)
#define OFF_SSRC  33528064u     // E ints
#define OFF_SDST  34168064u     // E ints
#define OFF_SIDX  34808064u     // E ints
#define WS_NEEDED 35448064u

extern "C" void kernel_launch(void* const* d_in, const int* in_sizes, int n_in,
                              void* d_out, int out_size, void* d_ws, size_t ws_size,
                              hipStream_t stream)
{
  const void* h      = d_in[0];
  const void* ea     = d_in[1];
  const void* msg_w1 = d_in[2];
  const void* msg_b1 = d_in[3];
  const void* msg_w2 = d_in[4];
  const void* msg_b2 = d_in[5];
  const void* upd_w1 = d_in[6];
  const void* upd_b1 = d_in[7];
  const void* upd_w2 = d_in[8];
  const void* upd_b2 = d_in[9];
  const void* norm_g = d_in[10];
  const void* norm_b = d_in[11];
  const void* em_w1  = d_in[12];
  const void* em_b1  = d_in[13];
  const void* em_w2  = d_in[14];
  const void* em_b2  = d_in[15];
  const void* eg_w   = d_in[16];
  const void* eg_b   = d_in[17];
  const void* en_g   = d_in[18];
  const void* en_b   = d_in[19];
  const int* eidx    = (const int*)d_in[20];
  const int* srcI = eidx;
  const int* dstI = eidx + N_EDGES;

  float sent = 0.f;
  if (ws_size < (size_t)WS_NEEDED)            sent = 1000.f;
  else if (n_in != 21)                        sent = 2000.f;
  else if (in_sizes[0]  != N_NODES * HD)      sent = 3000.f;
  else if (in_sizes[20] != 2 * N_EDGES)       sent = 4000.f;
  else if (out_size != N_NODES*HD + N_EDGES*EDD) sent = 5000.f;
  if (sent != 0.f){
    kfill<<<(out_size + 255)/256, 256, 0, stream>>>((u16*)d_out, out_size, sent);
    return;
  }

  char* ws = (char*)d_ws;
  float* S      = (float*)(ws + OFF_S);
  u16*   h2b    = (u16*)(ws + OFF_S);      // alias: after kupd1f consumed S
  int*   deg    = (int*)(ws + OFF_DEG);
  int*   cur    = (int*)(ws + OFF_CUR);
  int*   F      = (int*)(ws + OFF_F);
  int*   start  = (int*)(ws + OFF_START);
  u16*   P      = (u16*)(ws + OFF_AGGM);   // alias: P dead after kmsg5
  u16*   U      = (u16*)(ws + OFF_AGGM);
  u16*   W1T    = (u16*)(ws + OFF_W1T);
  u16*   WfT    = (u16*)(ws + OFF_W2T);
  u16*   PE     = (u16*)(ws + OFF_WU1T);   // alias: PE dead after kedge2
  u16*   WU1T   = (u16*)(ws + OFF_WU1T);
  u16*   WceT   = (u16*)(ws + OFF_WU2T);   // alias: WceT dead after kprePE
  u16*   WU2T   = (u16*)(ws + OFF_WU2T);
  float* bfused = (float*)(ws + OFF_WET);
  int*   sSrc   = (int*)(ws + OFF_SSRC);
  int*   sDst   = (int*)(ws + OFF_SDST);
  int*   sIdx   = (int*)(ws + OFF_SIDX);

  // hB (bf16 h) lives in d_out's h_out region (dead until kln rewrites it).
  u16* hB = (u16*)d_out;

  // zero S + deg + cursors in one memset (contiguous)
  hipMemsetAsync(S, 0, (size_t)OFF_F, stream);

  kprobe<<<1, 64, 0, stream>>>(h, ea, msg_w1, msg_w2, upd_w1, upd_w2,
                               em_w1, em_w2, eg_w, norm_g, en_g, F);

  // fused prep: hB convert + tiled W1T + WceT + j-parallel bfused
  kprep<<<2684, 256, 0, stream>>>(h, msg_w1, em_w1, eg_w, msg_b2, upd_w1, F,
                                  hB, W1T, WceT, bfused);

  kprePE<<<dim3(9, 79), 256, 0, stream>>>(hB, W1T, msg_b1, WceT, F, P, PE);

  kdeg<<<(N_EDGES + 255)/256, 256, 0, stream>>>(dstI, deg);
  kscan<<<1, 256, 0, stream>>>(deg, start);
  kscatter<<<(N_EDGES + 255)/256, 256, 0, stream>>>(srcI, dstI, start, cur,
                                                    sSrc, sDst, sIdx);

  kedge2<<<625, 256, 0, stream>>>(ea, PE, em_w1, em_w2, em_b1, em_b2, eg_w, eg_b,
                                  en_g, en_b, F, srcI, dstI, d_out);

  // PE/WceT dead -> tiled transposes of the update MLP, then Wf build
  kprep2<<<192, 256, 0, stream>>>(upd_w1, upd_w2, F, WU1T, WU2T);
  kWf<<<dim3(8, 4), 256, 0, stream>>>(WU1T, msg_w2, F, WfT);

  kmsg5<<<dim3(4, 1250), 256, 0, stream>>>(P, d_out, W1T, F,
                                           sSrc, sDst, sIdx, S);
  kupd1f<<<dim3(8, 79), 256, 0, stream>>>(hB, S, WU1T, WfT, upd_b1, bfused,
                                          deg, F, U);
  kupd2<<<dim3(8, 79), 256, 0, stream>>>(U, WU2T, upd_b2, F, h2b);
  kln<<<2500, 256, 0, stream>>>(h, h2b, norm_g, norm_b, F, d_out);
}

// Round 11
// 412.032 us; speedup vs baseline: 1.0163x; 1.0163x over previous
//
#include <hip/hip_runtime.h>

#define N_NODES 10000
#define N_EDGES 160000
#define HD 512
#define EDD 16

typedef unsigned short u16;
typedef __attribute__((ext_vector_type(8))) short bf16x8;
typedef __attribute__((ext_vector_type(4))) float f32x4;
typedef unsigned int u32;

__device__ __forceinline__ float bf2f(u16 u){
  unsigned int x = ((unsigned int)u) << 16;
  return __builtin_bit_cast(float, x);
}
__device__ __forceinline__ u16 f2bf(float f){
  unsigned int x = __builtin_bit_cast(unsigned int, f);
  unsigned int r = (x + 0x7fffu + ((x >> 16) & 1u)) >> 16;
  return (u16)r;
}
// dtype-flagged scalar load/store: flag!=0 -> f32, else bf16
__device__ __forceinline__ float ldx(const void* p, long long i, int f32){
  return f32 ? ((const float*)p)[i] : bf2f(((const u16*)p)[i]);
}
__device__ __forceinline__ void stx(void* p, long long i, int f32, float v){
  if (f32) ((float*)p)[i] = v; else ((u16*)p)[i] = f2bf(v);
}
// tanh-form gelu, NaN-free sigmoid form: x * rcp(1 + e^{-a})
__device__ __forceinline__ float gelu_f(float x){
  float c = x * x;
  float a = x * (1.5957691216f + 0.0713548162f * c);
  float e = __expf(-a);
  return x * __builtin_amdgcn_rcpf(1.0f + e);
}
__device__ __forceinline__ f32x4 mfma16(bf16x8 a, bf16x8 b, f32x4 c){
  return __builtin_amdgcn_mfma_f32_16x16x32_bf16(a, b, c, 0, 0, 0);
}
// LDS slot swizzle for [row][32]-u16 tiles (4 x 16B slots per row)
__device__ __forceinline__ int swz8(int row, int slot){
  return (slot ^ ((row >> 1) & 3)) * 8;
}
// load 8 contiguous elems as bf16x8 from f32-or-bf16 source (8-elem aligned)
__device__ __forceinline__ bf16x8 ld8(const void* p, long long i, int f32){
  if (!f32) return *(const bf16x8*)((const u16*)p + i);
  const float* q = (const float*)p + i;
  float4 a = *(const float4*)q, b = *(const float4*)(q + 4);
  u16 t[8] = { f2bf(a.x), f2bf(a.y), f2bf(a.z), f2bf(a.w),
               f2bf(b.x), f2bf(b.y), f2bf(b.z), f2bf(b.w) };
  return *(const bf16x8*)t;
}
__device__ __forceinline__ void stage8(const void* src, long long idx, int f32, u16* dst){
  bf16x8 v = ld8(src, idx, f32);
  *(bf16x8*)dst = v;
}

// ---------------- dtype probe
__device__ __forceinline__ int probe_rand(const void* p, int l){
  const u16* q = (const u16*)p;
  float mx = 0.f;
  #pragma unroll
  for (int i = 0; i < 4; ++i) mx = fmaxf(mx, fabsf(bf2f(q[l * 4 + i])));
  #pragma unroll
  for (int m = 1; m < 64; m <<= 1) mx = fmaxf(mx, __shfl_xor(mx, m, 64));
  return (mx > 1e3f) ? 1 : 0;
}
// F[0]=h F[1]=ea F[2]=msg_w1 F[3]=msg_w2 F[4]=upd_w1 F[5]=upd_w2
// F[6]=em_w1 F[7]=em_w2 F[8]=eg_w F[9]=norm_g F[10]=en_g F[11]=out(=h)
__global__ __launch_bounds__(64) void kprobe(
    const void* h, const void* ea, const void* mw1, const void* mw2,
    const void* uw1, const void* uw2, const void* ew1, const void* ew2,
    const void* egw, const void* ng, const void* eng, int* F)
{
  const int l = threadIdx.x;
  int f0 = probe_rand(h, l),   f1 = probe_rand(ea, l),  f2 = probe_rand(mw1, l);
  int f3 = probe_rand(mw2, l), f4 = probe_rand(uw1, l), f5 = probe_rand(uw2, l);
  int f6 = probe_rand(ew1, l), f7 = probe_rand(ew2, l), f8 = probe_rand(egw, l);
  if (l == 0){
    F[0] = f0; F[1] = f1; F[2] = f2; F[3] = f3; F[4] = f4; F[5] = f5;
    F[6] = f6; F[7] = f7; F[8] = f8;
    F[9]  = (((const u16*)ng)[0]  == 0) ? 1 : 0;
    F[10] = (((const u16*)eng)[0] == 0) ? 1 : 0;
    F[11] = f0;
  }
}

__global__ void kfill(u16* __restrict__ out, long long n, float val){
  long long i = (long long)blockIdx.x * 256 + threadIdx.x;
  if (i < n) out[i] = f2bf(val);
}

// ---------------- fused prep #1, grid 2684:
// [0,2500): hB convert  [2500,2572): W1T 64x64 LDS-tiled transpose
// [2572,2668): WceT build  [2668,2684): bfused (j-parallel x8, 32 n/block)
__global__ __launch_bounds__(256) void kprep(
    const void* __restrict__ h, const void* __restrict__ mw1,
    const void* __restrict__ ew1, const void* __restrict__ egw,
    const void* __restrict__ mb2, const void* __restrict__ uw1,
    const int* __restrict__ F,
    u16* __restrict__ hB, u16* __restrict__ W1T, u16* __restrict__ WceT,
    float* __restrict__ bfused)
{
  __shared__ float tl[64][65];
  const int b = blockIdx.x, tid = threadIdx.x;
  if (b < 2500){
    const long long i = ((long long)b * 256 + tid) * 8;
    if (i < (long long)N_NODES * HD)
      *(bf16x8*)(hB + i) = ld8(h, i, F[0]);
  } else if (b < 2572){
    // W1T[n][k] = (k<528) ? msg_w1[k][n] : 0 ; K=528->Kpad 544, N=512
    const int b2 = b - 2500;
    const int kt0 = (b2 >> 3) * 64, nt0 = (b2 & 7) * 64;
    const int ty = tid >> 6, tx = tid & 63;
    const int fw = F[2];
    #pragma unroll
    for (int q = 0; q < 16; ++q){
      const int r = ty * 16 + q;
      const int sr = kt0 + r;
      tl[r][tx] = (sr < 528) ? ldx(mw1, (long long)sr * 512 + nt0 + tx, fw) : 0.f;
    }
    __syncthreads();
    #pragma unroll
    for (int q = 0; q < 16; ++q){
      const int r = ty * 16 + q;
      const int k = kt0 + tx;
      if (k < 544) W1T[(size_t)(nt0 + r) * 544 + k] = f2bf(tl[tx][r]);
    }
  } else if (b < 2668){
    const int i = (b - 2572) * 256 + tid;
    const int c = i >> 9, k = i & 511;
    float v = 0.f;
    if (c < 16)       v = ldx(ew1, (long long)k * 16 + c, F[6]);
    else if (c < 32)  v = ldx(ew1, (long long)(512 + k) * 16 + (c - 16), F[6]);
    else if (c == 32) v = ldx(egw, k, F[8]);
    else if (c == 33) v = ldx(egw, 512 + k, F[8]);
    WceT[i] = f2bf(v);
  } else {
    // bfused[n] = sum_j msg_b2[j]*upd_w1[512+j][n]; 16 blocks x 32 n,
    // 8-way j-parallel per block (64-iter loop, coalesced row slices)
    float* ls   = &tl[0][0];          // 512 floats (b2 staged)
    float* part = &tl[0][0] + 1024;   // 8 x 33 partials
    const int f3 = F[3], f4 = F[4];
    for (int j = tid; j < 512; j += 256) ls[j] = ldx(mb2, j, f3);
    __syncthreads();
    const int nn = tid & 31, jg = tid >> 5;
    const int n = (b - 2668) * 32 + nn;
    float a = 0.f;
    for (int jj = 0; jj < 64; ++jj){
      const int j = jg * 64 + jj;
      a += ls[j] * ldx(uw1, (long long)(512 + j) * 512 + n, f4);
    }
    part[jg * 33 + nn] = a;
    __syncthreads();
    if (jg == 0){
      float s = a;
      #pragma unroll
      for (int g = 1; g < 8; ++g) s += part[g * 33 + nn];
      bfused[n] = s;
    }
  }
}

// ---------------- fused prep #2 (after kedge2 frees PE/WceT), grid 192:
// [0,128): WU1T tiled transpose (1024x512 -> [512][1024])
// [128,192): WU2T tiled transpose (512x512 -> [512][512])
__global__ __launch_bounds__(256) void kprep2(
    const void* __restrict__ uw1, const void* __restrict__ uw2,
    const int* __restrict__ F, u16* __restrict__ WU1T, u16* __restrict__ WU2T)
{
  __shared__ float tl[64][65];
  const int b = blockIdx.x, tid = threadIdx.x;
  const int ty = tid >> 6, tx = tid & 63;
  if (b < 128){
    const int kt0 = (b >> 3) * 64, nt0 = (b & 7) * 64;
    const int fw = F[4];
    #pragma unroll
    for (int q = 0; q < 16; ++q){
      const int r = ty * 16 + q;
      tl[r][tx] = ldx(uw1, (long long)(kt0 + r) * 512 + nt0 + tx, fw);
    }
    __syncthreads();
    #pragma unroll
    for (int q = 0; q < 16; ++q){
      const int r = ty * 16 + q;
      WU1T[(size_t)(nt0 + r) * 1024 + kt0 + tx] = f2bf(tl[tx][r]);
    }
  } else {
    const int b2 = b - 128;
    const int kt0 = (b2 >> 3) * 64, nt0 = (b2 & 7) * 64;
    const int fw = F[5];
    #pragma unroll
    for (int q = 0; q < 16; ++q){
      const int r = ty * 16 + q;
      tl[r][tx] = ldx(uw2, (long long)(kt0 + r) * 512 + nt0 + tx, fw);
    }
    __syncthreads();
    #pragma unroll
    for (int q = 0; q < 16; ++q){
      const int r = ty * 16 + q;
      WU2T[(size_t)(nt0 + r) * 512 + kt0 + tx] = f2bf(tl[tx][r]);
    }
  }
}

__global__ void kdeg(const int* __restrict__ dst, int* __restrict__ deg){
  int e = blockIdx.x * 256 + threadIdx.x;
  if (e < N_EDGES) atomicAdd(&deg[dst[e]], 1);
}

// ---------------- exclusive scan of deg -> start
__global__ __launch_bounds__(256) void kscan(const int* __restrict__ deg,
                                             int* __restrict__ start){
  __shared__ int ls[256];
  const int t = threadIdx.x;
  const int base = t * 40;
  int s = 0;
  for (int i = 0; i < 40; ++i){ int idx = base + i; if (idx < N_NODES) s += deg[idx]; }
  ls[t] = s; __syncthreads();
  for (int off = 1; off < 256; off <<= 1){
    int v = (t >= off) ? ls[t - off] : 0;
    __syncthreads();
    ls[t] += v;
    __syncthreads();
  }
  int run = (t == 0) ? 0 : ls[t - 1];
  for (int i = 0; i < 40; ++i){
    int idx = base + i;
    if (idx < N_NODES){ start[idx] = run; run += deg[idx]; }
  }
}

// ---------------- counting-sort scatter: edges sorted by dst
__global__ void kscatter(const int* __restrict__ srcI, const int* __restrict__ dstI,
                         const int* __restrict__ start, int* __restrict__ cursor,
                         int* __restrict__ sSrc, int* __restrict__ sDst,
                         int* __restrict__ sIdx){
  int e = blockIdx.x * 256 + threadIdx.x;
  if (e < N_EDGES){
    int d = dstI[e];
    int p = start[d] + atomicAdd(&cursor[d], 1);
    sSrc[p] = srcI[e]; sDst[p] = d; sIdx[p] = e;
  }
}

// ---------------- fused: P = bf16(h @ msg_w1[:512] + b1) (x<8, BM128 BN64)
//                  and PE = bf16(h @ WceT^T) [N][48]     (x==8)
// grid (9,79): same-row-panel blocks adjacent in dispatch -> hB L2 reuse
__global__ __launch_bounds__(256, 4) void kprePE(
    const u16* __restrict__ hB, const u16* __restrict__ W1T,
    const void* __restrict__ msg_b1, const u16* __restrict__ WceT,
    const int* __restrict__ F, u16* __restrict__ P, u16* __restrict__ PE)
{
  __shared__ u16 As[128 * 32];
  __shared__ u16 Bs[64 * 32];
  const int tid = threadIdx.x;
  const int row0 = blockIdx.y * 128;
  const int w = tid >> 6, l = tid & 63;
  const int lm = l & 15, lk = l >> 4;
  if (blockIdx.x < 8){
    const int fw = F[2];
    const int n0 = blockIdx.x * 64;
    f32x4 acc[2][4];
    f32x4 z4 = {0.f, 0.f, 0.f, 0.f};
    #pragma unroll
    for (int i = 0; i < 2; ++i)
      #pragma unroll
      for (int j = 0; j < 4; ++j) acc[i][j] = z4;
    const int nB = tid >> 2, kqB = tid & 3;
    for (int kt = 0; kt < 16; ++kt){
      const int kk = kt * 32;
      #pragma unroll
      for (int i = 0; i < 2; ++i){
        int t = tid + i * 256;
        int m = t >> 2, kq = t & 3;
        int gr = row0 + m; if (gr > N_NODES - 1) gr = N_NODES - 1;
        *(uint4*)&As[m * 32 + swz8(m, kq)] = *(const uint4*)(hB + (size_t)gr * HD + kk + kq * 8);
      }
      *(uint4*)&Bs[nB * 32 + swz8(nB, kqB)] =
          *(const uint4*)(W1T + (size_t)(n0 + nB) * 544 + kk + kqB * 8);
      __syncthreads();
      bf16x8 af[2], bfv[4];
      #pragma unroll
      for (int i = 0; i < 2; ++i){
        const int R = w * 32 + i * 16 + lm;
        af[i] = *(const bf16x8*)&As[R * 32 + swz8(R, lk)];
      }
      #pragma unroll
      for (int j = 0; j < 4; ++j){
        const int R = j * 16 + lm;
        bfv[j] = *(const bf16x8*)&Bs[R * 32 + swz8(R, lk)];
      }
      #pragma unroll
      for (int i = 0; i < 2; ++i)
        #pragma unroll
        for (int j = 0; j < 4; ++j)
          acc[i][j] = mfma16(af[i], bfv[j], acc[i][j]);
      __syncthreads();
    }
    #pragma unroll
    for (int j = 0; j < 4; ++j){
      const int col = n0 + j * 16 + lm;
      const float bias = ldx(msg_b1, col, fw);
      #pragma unroll
      for (int i = 0; i < 2; ++i){
        const int rb = row0 + w * 32 + i * 16 + lk * 4;
        #pragma unroll
        for (int r = 0; r < 4; ++r){
          int gr = rb + r;
          if (gr < N_NODES)
            P[(size_t)gr * HD + col] = f2bf(acc[i][j][r] + bias);
        }
      }
    }
  } else {
    f32x4 acc[2][3];
    f32x4 z4 = {0.f, 0.f, 0.f, 0.f};
    #pragma unroll
    for (int i = 0; i < 2; ++i)
      #pragma unroll
      for (int j = 0; j < 3; ++j) acc[i][j] = z4;
    for (int kt = 0; kt < 16; ++kt){
      const int kk = kt * 32;
      #pragma unroll
      for (int i = 0; i < 2; ++i){
        int t = tid + i * 256;
        int m = t >> 2, kq = t & 3;
        int gr = row0 + m; if (gr > N_NODES - 1) gr = N_NODES - 1;
        *(uint4*)&As[m * 32 + swz8(m, kq)] = *(const uint4*)(hB + (size_t)gr * HD + kk + kq * 8);
      }
      if (tid < 192){
        int c = tid >> 2, kq = tid & 3;
        *(uint4*)&Bs[c * 32 + swz8(c, kq)] =
            *(const uint4*)(WceT + (size_t)c * 512 + kk + kq * 8);
      }
      __syncthreads();
      bf16x8 af[2], bfv[3];
      #pragma unroll
      for (int i = 0; i < 2; ++i){
        const int R = w * 32 + i * 16 + lm;
        af[i] = *(const bf16x8*)&As[R * 32 + swz8(R, lk)];
      }
      #pragma unroll
      for (int j = 0; j < 3; ++j){
        const int R = j * 16 + lm;
        bfv[j] = *(const bf16x8*)&Bs[R * 32 + swz8(R, lk)];
      }
      #pragma unroll
      for (int i = 0; i < 2; ++i)
        #pragma unroll
        for (int j = 0; j < 3; ++j)
          acc[i][j] = mfma16(af[i], bfv[j], acc[i][j]);
      __syncthreads();
    }
    #pragma unroll
    for (int j = 0; j < 3; ++j){
      const int col = j * 16 + lm;
      #pragma unroll
      for (int i = 0; i < 2; ++i){
        const int rb = row0 + w * 32 + i * 16 + lk * 4;
        #pragma unroll
        for (int r = 0; r < 4; ++r){
          int gr = rb + r;
          if (gr < N_NODES)
            PE[(size_t)gr * 48 + col] = f2bf(acc[i][j][r]);
        }
      }
    }
  }
}

// ---------------- edge update, decomposed: 1 thread = 1 edge, grid 625
__global__ __launch_bounds__(256) void kedge2(
    const void* __restrict__ ea, const u16* __restrict__ PE,
    const void* __restrict__ em_w1, const void* __restrict__ em_w2,
    const void* __restrict__ em_b1, const void* __restrict__ em_b2,
    const void* __restrict__ eg_w, const void* __restrict__ eg_b,
    const void* __restrict__ en_g, const void* __restrict__ en_b,
    const int* __restrict__ F,
    const int* __restrict__ srcI, const int* __restrict__ dstI,
    void* __restrict__ dout)
{
  __shared__ float wt[16][17];
  __shared__ float w2s[256];
  __shared__ float egt[16], b1e[16], b2s[16], gns[16], bns[16];
  __shared__ float egb_s;
  const int tid = threadIdx.x;
  const int fea = F[1], fem1 = F[6], fem2 = F[7], feg = F[8];
  const int fen = F[10], fo = F[11];
  { int k = tid >> 4, j = tid & 15;
    wt[k][j] = ldx(em_w1, (long long)(1024 + k) * 16 + j, fem1); }
  w2s[tid] = ldx(em_w2, tid, fem2);
  if (tid < 16){
    egt[tid] = ldx(eg_w, 1024 + tid, feg);
    b1e[tid] = ldx(em_b1, tid, fem1);
    b2s[tid] = ldx(em_b2, tid, fem2);
    gns[tid] = ldx(en_g, tid, fen);
    bns[tid] = ldx(en_b, tid, fen);
  }
  if (tid == 0) egb_s = ldx(eg_b, 0, feg);
  __syncthreads();

  const int e = blockIdx.x * 256 + tid;
  const int s = srcI[e], d = dstI[e];
  float earr[16];
  if (fea){
    const float4* q = (const float4*)((const float*)ea + (size_t)e * 16);
    float4 v0 = q[0], v1 = q[1], v2 = q[2], v3 = q[3];
    earr[0]=v0.x; earr[1]=v0.y; earr[2]=v0.z; earr[3]=v0.w;
    earr[4]=v1.x; earr[5]=v1.y; earr[6]=v1.z; earr[7]=v1.w;
    earr[8]=v2.x; earr[9]=v2.y; earr[10]=v2.z; earr[11]=v2.w;
    earr[12]=v3.x; earr[13]=v3.y; earr[14]=v3.z; earr[15]=v3.w;
  } else {
    const u16* q = (const u16*)ea + (size_t)e * 16;
    bf16x8 a = *(const bf16x8*)q, b = *(const bf16x8*)(q + 8);
    #pragma unroll
    for (int j = 0; j < 8; ++j){ earr[j] = bf2f((u16)a[j]); earr[8 + j] = bf2f((u16)b[j]); }
  }
  const u16* prs = PE + (size_t)s * 48;
  const u16* prd = PE + (size_t)d * 48;
  bf16x8 ps0 = *(const bf16x8*)prs,        ps1 = *(const bf16x8*)(prs + 8);
  bf16x8 pd0 = *(const bf16x8*)(prd + 16), pd1 = *(const bf16x8*)(prd + 24);
  const float gs = bf2f(prs[32]), gd = bf2f(prd[33]);
  float t[16];
  #pragma unroll
  for (int j = 0; j < 8; ++j){
    t[j]     = bf2f((u16)ps0[j]) + bf2f((u16)pd0[j]) + b1e[j];
    t[8 + j] = bf2f((u16)ps1[j]) + bf2f((u16)pd1[j]) + b1e[8 + j];
  }
  float gl = gs + gd + egb_s;
  #pragma unroll
  for (int k = 0; k < 16; ++k){
    const float ek = earr[k];
    gl += ek * egt[k];
    #pragma unroll
    for (int j = 0; j < 16; ++j) t[j] += ek * wt[k][j];
  }
  const float gate = __builtin_amdgcn_rcpf(1.0f + __expf(-gl));
  float gj[16];
  #pragma unroll
  for (int j = 0; j < 16; ++j) gj[j] = gelu_f(t[j]);
  float rv[16]; float s1 = 0.f, s2 = 0.f;
  #pragma unroll
  for (int j = 0; j < 16; ++j){
    float dlt = b2s[j];
    #pragma unroll
    for (int k = 0; k < 16; ++k) dlt += gj[k] * w2s[k * 16 + j];
    rv[j] = earr[j] + 0.1f * gate * dlt;
    s1 += rv[j]; s2 += rv[j] * rv[j];
  }
  const float mu  = s1 * (1.f / 16.f);
  const float var = s2 * (1.f / 16.f) - mu * mu;
  const float inv = rsqrtf(var + 1e-5f);
  if (fo){
    float* ob = (float*)dout + (size_t)N_NODES * HD + (size_t)e * 16;
    #pragma unroll
    for (int j = 0; j < 16; ++j) ob[j] = (rv[j] - mu) * inv * gns[j] + bns[j];
  } else {
    u16 tmp[16];
    #pragma unroll
    for (int j = 0; j < 16; ++j) tmp[j] = f2bf((rv[j] - mu) * inv * gns[j] + bns[j]);
    u16* ob = (u16*)dout + (size_t)N_NODES * HD + (size_t)e * 16;
    *(uint4*)ob = *(uint4*)&tmp[0];
    *(uint4*)(ob + 8) = *(uint4*)&tmp[8];
  }
}

// ---------------- WfT[n][k] = sum_j WU1T[n][512+j] * msg_w2[k][j]
// grid (8,4): x=colblock, y=rowblock
__global__ __launch_bounds__(256, 4) void kWf(
    const u16* __restrict__ WU1T, const void* __restrict__ mw2,
    const int* __restrict__ F, u16* __restrict__ WfT)
{
  __shared__ u16 As[128 * 32];
  __shared__ u16 Bs[64 * 32];
  const int tid = threadIdx.x;
  const int f3 = F[3];
  const int row0 = blockIdx.y * 128, n0 = blockIdx.x * 64;
  f32x4 acc[2][4];
  f32x4 z4 = {0.f, 0.f, 0.f, 0.f};
  #pragma unroll
  for (int i = 0; i < 2; ++i)
    #pragma unroll
    for (int j = 0; j < 4; ++j) acc[i][j] = z4;
  const int w = tid >> 6, l = tid & 63;
  const int lm = l & 15, lk = l >> 4;
  const int nB = tid >> 2, kqB = tid & 3;
  for (int kt = 0; kt < 16; ++kt){
    const int kk = kt * 32;
    #pragma unroll
    for (int i = 0; i < 2; ++i){
      int t = tid + i * 256;
      int m = t >> 2, kq = t & 3;
      *(uint4*)&As[m * 32 + swz8(m, kq)] =
          *(const uint4*)(WU1T + (size_t)(row0 + m) * 1024 + 512 + kk + kq * 8);
    }
    stage8(mw2, (long long)(n0 + nB) * 512 + kk + kqB * 8, f3,
           &Bs[nB * 32 + swz8(nB, kqB)]);
    __syncthreads();
    bf16x8 af[2], bfv[4];
    #pragma unroll
    for (int i = 0; i < 2; ++i){
      const int R = w * 32 + i * 16 + lm;
      af[i] = *(const bf16x8*)&As[R * 32 + swz8(R, lk)];
    }
    #pragma unroll
    for (int j = 0; j < 4; ++j){
      const int R = j * 16 + lm;
      bfv[j] = *(const bf16x8*)&Bs[R * 32 + swz8(R, lk)];
    }
    #pragma unroll
    for (int i = 0; i < 2; ++i)
      #pragma unroll
      for (int j = 0; j < 4; ++j)
        acc[i][j] = mfma16(af[i], bfv[j], acc[i][j]);
    __syncthreads();
  }
  #pragma unroll
  for (int j = 0; j < 4; ++j){
    const int col = n0 + j * 16 + lm;
    #pragma unroll
    for (int i = 0; i < 2; ++i){
      const int rb = row0 + w * 32 + i * 16 + lk * 4;
      #pragma unroll
      for (int r = 0; r < 4; ++r)
        WfT[(size_t)(rb + r) * 512 + col] = f2bf(acc[i][j][r]);
    }
  }
}

// ---------------- message via single K=32 MFMA tile + P-gather + segmented
// reduce (proven round-9 version: scalar P gathers hit L1; do NOT stage P)
__global__ __launch_bounds__(256, 4) void kmsg4(
    const u16* __restrict__ P, const void* __restrict__ dout,
    const u16* __restrict__ W1T, const int* __restrict__ F,
    const int* __restrict__ sSrc, const int* __restrict__ sDst,
    const int* __restrict__ sIdx,
    float* __restrict__ agg)
{
  __shared__ __align__(16) float SMEM[4352];
  u16*   As = (u16*)SMEM;
  u16*   Bs = (u16*)SMEM + 4096;
  float* Sf = SMEM;
  __shared__ int src_s[128];
  __shared__ int dst_s[128];
  const int tid = threadIdx.x;
  const int fo = F[11];
  const void* e_base = fo ? (const void*)((const float*)dout + (size_t)N_NODES * HD)
                          : (const void*)((const u16*)dout + (size_t)N_NODES * HD);
  const int row0 = blockIdx.x * 128, n0 = blockIdx.y * 128;
  if (tid < 128){
    src_s[tid] = sSrc[row0 + tid];
    dst_s[tid] = sDst[row0 + tid];
  }
  #pragma unroll
  for (int i = 0; i < 2; ++i){
    int t = tid + i * 256;
    int m = t >> 2, kq = t & 3;
    if (kq < 2){
      const long long ie = sIdx[row0 + m];
      stage8(e_base, ie * EDD + kq * 8, fo, &As[m * 32 + swz8(m, kq)]);
      *(uint4*)&Bs[m * 32 + swz8(m, kq)] =
          *(const uint4*)(W1T + (size_t)(n0 + m) * 544 + 512 + kq * 8);
    } else {
      uint4 z = {0,0,0,0};
      *(uint4*)&As[m * 32 + swz8(m, kq)] = z;
      *(uint4*)&Bs[m * 32 + swz8(m, kq)] = z;
    }
  }
  __syncthreads();
  const int w = tid >> 6, l = tid & 63;
  const int wr = w >> 1, wc = w & 1, lm = l & 15, lk = l >> 4;
  f32x4 acc[4][4];
  bf16x8 af[4], bfv[4];
  #pragma unroll
  for (int i = 0; i < 4; ++i){
    const int R = wr * 64 + i * 16 + lm;
    af[i] = *(const bf16x8*)&As[R * 32 + swz8(R, lk)];
  }
  #pragma unroll
  for (int j = 0; j < 4; ++j){
    const int R = wc * 64 + j * 16 + lm;
    bfv[j] = *(const bf16x8*)&Bs[R * 32 + swz8(R, lk)];
  }
  f32x4 z4 = {0.f, 0.f, 0.f, 0.f};
  #pragma unroll
  for (int i = 0; i < 4; ++i)
    #pragma unroll
    for (int j = 0; j < 4; ++j)
      acc[i][j] = mfma16(af[i], bfv[j], z4);
  u32 poff[4][4];
  #pragma unroll
  for (int i = 0; i < 4; ++i)
    #pragma unroll
    for (int r = 0; r < 4; ++r)
      poff[i][r] = (u32)src_s[wr * 64 + i * 16 + lk * 4 + r] * HD;
  const int cj = tid & 31, chunk = tid >> 5;
  const int rbase = chunk * 16;
  u32 aoff[16]; unsigned maskb = 0;
  {
    int dprev = dst_s[rbase];
    aoff[0] = (u32)dprev * HD;
    #pragma unroll
    for (int rr = 1; rr < 16; ++rr){
      const int dn = dst_s[rbase + rr];
      if (dn == dprev) maskb |= (1u << rr);
      aoff[rr] = (u32)dn * HD;
      dprev = dn;
    }
  }
  __syncthreads();
  const int sfb = wc * 16 + lm;
  #pragma unroll
  for (int j = 0; j < 4; ++j){
    const int col = n0 + wc * 64 + j * 16 + lm;
    #pragma unroll
    for (int i = 0; i < 4; ++i){
      #pragma unroll
      for (int r = 0; r < 4; ++r){
        const int row = wr * 64 + i * 16 + lk * 4 + r;
        const float pv = bf2f(P[poff[i][r] + col]);
        Sf[row * 34 + sfb] = gelu_f(acc[i][j][r] + pv);
      }
    }
    __syncthreads();
    const int acol = n0 + (cj >> 4) * 64 + j * 16 + (cj & 15);
    float run = Sf[rbase * 34 + cj];
    #pragma unroll
    for (int rr = 1; rr < 16; ++rr){
      const float v = Sf[(rbase + rr) * 34 + cj];
      if (maskb & (1u << rr)) run += v;
      else { atomicAdd(&agg[(size_t)aoff[rr - 1] + acol], run); run = v; }
    }
    atomicAdd(&agg[(size_t)aoff[15] + acol], run);
    __syncthreads();
  }
}

// ---------------- U = bf16(gelu(h@W1u_top + S@Wf + deg*bfused + b1u))
// grid (8,79): x=colblock (BN=64), y=rowblock (BM=128), K=1024
__global__ __launch_bounds__(256, 4) void kupd1f(
    const u16* __restrict__ hB, const float* __restrict__ S,
    const u16* __restrict__ WU1T, const u16* __restrict__ WfT,
    const void* __restrict__ upd_b1, const float* __restrict__ bfused,
    const int* __restrict__ deg, const int* __restrict__ F,
    u16* __restrict__ U)
{
  __shared__ u16 As[128 * 32];
  __shared__ u16 Bs[64 * 32];
  const int tid = threadIdx.x;
  const int fw = F[4];
  const int row0 = blockIdx.y * 128, n0 = blockIdx.x * 64;
  f32x4 acc[2][4];
  f32x4 z4 = {0.f, 0.f, 0.f, 0.f};
  #pragma unroll
  for (int i = 0; i < 2; ++i)
    #pragma unroll
    for (int j = 0; j < 4; ++j) acc[i][j] = z4;
  const int w = tid >> 6, l = tid & 63;
  const int lm = l & 15, lk = l >> 4;
  const int nB = tid >> 2, kqB = tid & 3;
  const int am = tid >> 1, ah = tid & 1;
  const int agr = row0 + am;
  for (int kt = 0; kt < 32; ++kt){
    const int kk = kt * 32;
    if (kk < 512){
      #pragma unroll
      for (int i = 0; i < 2; ++i){
        int t = tid + i * 256;
        int m = t >> 2, kq = t & 3;
        int gr = row0 + m; if (gr > N_NODES - 1) gr = N_NODES - 1;
        *(uint4*)&As[m * 32 + swz8(m, kq)] = *(const uint4*)(hB + (size_t)gr * HD + kk + kq * 8);
      }
      *(uint4*)&Bs[nB * 32 + swz8(nB, kqB)] =
          *(const uint4*)(WU1T + (size_t)(n0 + nB) * 1024 + kk + kqB * 8);
    } else {
      const int ks = kk - 512;
      u16 tmp[16];
      if (agr < N_NODES){
        const float4* sp = (const float4*)(S + (size_t)agr * HD + ks + ah * 16);
        #pragma unroll
        for (int q = 0; q < 4; ++q){
          float4 v = sp[q];
          tmp[q*4+0] = f2bf(v.x); tmp[q*4+1] = f2bf(v.y);
          tmp[q*4+2] = f2bf(v.z); tmp[q*4+3] = f2bf(v.w);
        }
      } else {
        #pragma unroll
        for (int q = 0; q < 16; ++q) tmp[q] = 0;
      }
      *(uint4*)&As[am * 32 + swz8(am, ah * 2)]     = *(uint4*)&tmp[0];
      *(uint4*)&As[am * 32 + swz8(am, ah * 2 + 1)] = *(uint4*)&tmp[8];
      *(uint4*)&Bs[nB * 32 + swz8(nB, kqB)] =
          *(const uint4*)(WfT + (size_t)(n0 + nB) * 512 + ks + kqB * 8);
    }
    __syncthreads();
    bf16x8 af[2], bfv[4];
    #pragma unroll
    for (int i = 0; i < 2; ++i){
      const int R = w * 32 + i * 16 + lm;
      af[i] = *(const bf16x8*)&As[R * 32 + swz8(R, lk)];
    }
    #pragma unroll
    for (int j = 0; j < 4; ++j){
      const int R = j * 16 + lm;
      bfv[j] = *(const bf16x8*)&Bs[R * 32 + swz8(R, lk)];
    }
    #pragma unroll
    for (int i = 0; i < 2; ++i)
      #pragma unroll
      for (int j = 0; j < 4; ++j)
        acc[i][j] = mfma16(af[i], bfv[j], acc[i][j]);
    __syncthreads();
  }
  #pragma unroll
  for (int j = 0; j < 4; ++j){
    const int col = n0 + j * 16 + lm;
    const float bias = ldx(upd_b1, col, fw);
    const float bfv2 = bfused[col];
    #pragma unroll
    for (int i = 0; i < 2; ++i){
      const int rb = row0 + w * 32 + i * 16 + lk * 4;
      #pragma unroll
      for (int r = 0; r < 4; ++r){
        int gr = rb + r;
        if (gr < N_NODES)
          U[(size_t)gr * HD + col] =
              f2bf(gelu_f(acc[i][j][r] + bias + (float)deg[gr] * bfv2));
      }
    }
  }
}

// ---------------- h2b = bf16(U @ upd_w2 + b2)   grid (8,79), K=512
__global__ __launch_bounds__(256, 4) void kupd2(
    const u16* __restrict__ U, const u16* __restrict__ WU2T,
    const void* __restrict__ upd_b2, const int* __restrict__ F,
    u16* __restrict__ h2b)
{
  __shared__ u16 As[128 * 32];
  __shared__ u16 Bs[64 * 32];
  const int tid = threadIdx.x;
  const int fw = F[5];
  const int row0 = blockIdx.y * 128, n0 = blockIdx.x * 64;
  f32x4 acc[2][4];
  f32x4 z4 = {0.f, 0.f, 0.f, 0.f};
  #pragma unroll
  for (int i = 0; i < 2; ++i)
    #pragma unroll
    for (int j = 0; j < 4; ++j) acc[i][j] = z4;
  const int w = tid >> 6, l = tid & 63;
  const int lm = l & 15, lk = l >> 4;
  const int nB = tid >> 2, kqB = tid & 3;
  for (int kt = 0; kt < 16; ++kt){
    const int kk = kt * 32;
    #pragma unroll
    for (int i = 0; i < 2; ++i){
      int t = tid + i * 256;
      int m = t >> 2, kq = t & 3;
      int gr = row0 + m; if (gr > N_NODES - 1) gr = N_NODES - 1;
      *(uint4*)&As[m * 32 + swz8(m, kq)] = *(const uint4*)(U + (size_t)gr * HD + kk + kq * 8);
    }
    *(uint4*)&Bs[nB * 32 + swz8(nB, kqB)] =
        *(const uint4*)(WU2T + (size_t)(n0 + nB) * 512 + kk + kqB * 8);
    __syncthreads();
    bf16x8 af[2], bfv[4];
    #pragma unroll
    for (int i = 0; i < 2; ++i){
      const int R = w * 32 + i * 16 + lm;
      af[i] = *(const bf16x8*)&As[R * 32 + swz8(R, lk)];
    }
    #pragma unroll
    for (int j = 0; j < 4; ++j){
      const int R = j * 16 + lm;
      bfv[j] = *(const bf16x8*)&Bs[R * 32 + swz8(R, lk)];
    }
    #pragma unroll
    for (int i = 0; i < 2; ++i)
      #pragma unroll
      for (int j = 0; j < 4; ++j)
        acc[i][j] = mfma16(af[i], bfv[j], acc[i][j]);
    __syncthreads();
  }
  #pragma unroll
  for (int j = 0; j < 4; ++j){
    const int col = n0 + j * 16 + lm;
    const float bias = ldx(upd_b2, col, fw);
    #pragma unroll
    for (int i = 0; i < 2; ++i){
      const int rb = row0 + w * 32 + i * 16 + lk * 4;
      #pragma unroll
      for (int r = 0; r < 4; ++r){
        int gr = rb + r;
        if (gr < N_NODES)
          h2b[(size_t)gr * HD + col] = f2bf(acc[i][j][r] + bias);
      }
    }
  }
}

// ---------------- h_out = LN(h + h2)   grid 2500, 4 rows/block
__global__ __launch_bounds__(256) void kln(
    const void* __restrict__ h, const u16* __restrict__ h2b,
    const void* __restrict__ gg, const void* __restrict__ bbv,
    const int* __restrict__ F, void* __restrict__ dout)
{
  const int fh = F[0], fng = F[9], fo = F[11];
  const int w = threadIdx.x >> 6, l = threadIdx.x & 63;
  const int row = blockIdx.x * 4 + w;
  float x[8];
  #pragma unroll
  for (int j = 0; j < 8; ++j){
    const long long idx = (long long)row * HD + l * 8 + j;
    x[j] = ldx(h, idx, fh) + bf2f(h2b[idx]);
  }
  float s1 = 0.f, s2 = 0.f;
  #pragma unroll
  for (int j = 0; j < 8; ++j){ s1 += x[j]; s2 += x[j] * x[j]; }
  #pragma unroll
  for (int m = 1; m < 64; m <<= 1){ s1 += __shfl_xor(s1, m, 64); s2 += __shfl_xor(s2, m, 64); }
  const float mu  = s1 * (1.f / 512.f);
  const float var = s2 * (1.f / 512.f) - mu * mu;
  const float inv = rsqrtf(var + 1e-5f);
  #pragma unroll
  for (int j = 0; j < 8; ++j){
    const float gf = ldx(gg,  l * 8 + j, fng);
    const float bf = ldx(bbv, l * 8 + j, fng);
    stx(dout, (long long)row * HD + l * 8 + j, fo, (x[j] - mu) * inv * gf + bf);
  }
}

// ---------------- workspace layout (bytes), total 35,448,064 (unchanged)
#define OFF_S     0u            // N*512 f32 (scatter accum; later h2b bf16)
#define OFF_DEG   20480000u     // N ints
#define OFF_CUR   20520000u     // N ints (sort cursors)
#define OFF_F     20560000u     // 16 ints
#define OFF_START 20560064u     // N ints
#define OFF_AGGM  20600064u     // N*512 bf16 (P, then U)
#define OFF_W1T   30840064u     // 512*544 bf16
#define OFF_W2T   31397120u     // 512*512 bf16 (WfT)
#define OFF_WU1T  31921408u     // 512*1024 bf16 (PE first)
#define OFF_WU2T  32969984u     // 512*512 bf16 (WceT first)
#define OFF_WET   33494272u     // bfused (512 f32)
#define OFF_SSRC  33528064u     // E ints
#define OFF_SDST  34168064u     // E ints
#define OFF_SIDX  34808064u     // E ints
#define WS_NEEDED 35448064u

extern "C" void kernel_launch(void* const* d_in, const int* in_sizes, int n_in,
                              void* d_out, int out_size, void* d_ws, size_t ws_size,
                              hipStream_t stream)
{
  const void* h      = d_in[0];
  const void* ea     = d_in[1];
  const void* msg_w1 = d_in[2];
  const void* msg_b1 = d_in[3];
  const void* msg_w2 = d_in[4];
  const void* msg_b2 = d_in[5];
  const void* upd_w1 = d_in[6];
  const void* upd_b1 = d_in[7];
  const void* upd_w2 = d_in[8];
  const void* upd_b2 = d_in[9];
  const void* norm_g = d_in[10];
  const void* norm_b = d_in[11];
  const void* em_w1  = d_in[12];
  const void* em_b1  = d_in[13];
  const void* em_w2  = d_in[14];
  const void* em_b2  = d_in[15];
  const void* eg_w   = d_in[16];
  const void* eg_b   = d_in[17];
  const void* en_g   = d_in[18];
  const void* en_b   = d_in[19];
  const int* eidx    = (const int*)d_in[20];
  const int* srcI = eidx;
  const int* dstI = eidx + N_EDGES;

  float sent = 0.f;
  if (ws_size < (size_t)WS_NEEDED)            sent = 1000.f;
  else if (n_in != 21)                        sent = 2000.f;
  else if (in_sizes[0]  != N_NODES * HD)      sent = 3000.f;
  else if (in_sizes[20] != 2 * N_EDGES)       sent = 4000.f;
  else if (out_size != N_NODES*HD + N_EDGES*EDD) sent = 5000.f;
  if (sent != 0.f){
    kfill<<<(out_size + 255)/256, 256, 0, stream>>>((u16*)d_out, out_size, sent);
    return;
  }

  char* ws = (char*)d_ws;
  float* S      = (float*)(ws + OFF_S);
  u16*   h2b    = (u16*)(ws + OFF_S);      // alias: after kupd1f consumed S
  int*   deg    = (int*)(ws + OFF_DEG);
  int*   cur    = (int*)(ws + OFF_CUR);
  int*   F      = (int*)(ws + OFF_F);
  int*   start  = (int*)(ws + OFF_START);
  u16*   P      = (u16*)(ws + OFF_AGGM);   // alias: P dead after kmsg4
  u16*   U      = (u16*)(ws + OFF_AGGM);
  u16*   W1T    = (u16*)(ws + OFF_W1T);
  u16*   WfT    = (u16*)(ws + OFF_W2T);
  u16*   PE     = (u16*)(ws + OFF_WU1T);   // alias: PE dead after kedge2
  u16*   WU1T   = (u16*)(ws + OFF_WU1T);
  u16*   WceT   = (u16*)(ws + OFF_WU2T);   // alias: WceT dead after kprePE
  u16*   WU2T   = (u16*)(ws + OFF_WU2T);
  float* bfused = (float*)(ws + OFF_WET);
  int*   sSrc   = (int*)(ws + OFF_SSRC);
  int*   sDst   = (int*)(ws + OFF_SDST);
  int*   sIdx   = (int*)(ws + OFF_SIDX);

  // hB (bf16 h) lives in d_out's h_out region (dead until kln rewrites it).
  u16* hB = (u16*)d_out;

  // zero S + deg + cursors in one memset (contiguous)
  hipMemsetAsync(S, 0, (size_t)OFF_F, stream);

  kprobe<<<1, 64, 0, stream>>>(h, ea, msg_w1, msg_w2, upd_w1, upd_w2,
                               em_w1, em_w2, eg_w, norm_g, en_g, F);

  // fused prep: hB convert + tiled W1T + WceT + j-parallel bfused
  kprep<<<2684, 256, 0, stream>>>(h, msg_w1, em_w1, eg_w, msg_b2, upd_w1, F,
                                  hB, W1T, WceT, bfused);

  kprePE<<<dim3(9, 79), 256, 0, stream>>>(hB, W1T, msg_b1, WceT, F, P, PE);

  kdeg<<<(N_EDGES + 255)/256, 256, 0, stream>>>(dstI, deg);
  kscan<<<1, 256, 0, stream>>>(deg, start);
  kscatter<<<(N_EDGES + 255)/256, 256, 0, stream>>>(srcI, dstI, start, cur,
                                                    sSrc, sDst, sIdx);

  kedge2<<<625, 256, 0, stream>>>(ea, PE, em_w1, em_w2, em_b1, em_b2, eg_w, eg_b,
                                  en_g, en_b, F, srcI, dstI, d_out);

  // PE/WceT dead -> tiled transposes of the update MLP, then Wf build
  kprep2<<<192, 256, 0, stream>>>(upd_w1, upd_w2, F, WU1T, WU2T);
  kWf<<<dim3(8, 4), 256, 0, stream>>>(WU1T, msg_w2, F, WfT);

  kmsg4<<<dim3(1250, 4), 256, 0, stream>>>(P, d_out, W1T, F,
                                           sSrc, sDst, sIdx, S);
  kupd1f<<<dim3(8, 79), 256, 0, stream>>>(hB, S, WU1T, WfT, upd_b1, bfused,
                                          deg, F, U);
  kupd2<<<dim3(8, 79), 256, 0, stream>>>(U, WU2T, upd_b2, F, h2b);
  kln<<<2500, 256, 0, stream>>>(h, h2b, norm_g, norm_b, F, d_out);
}

// Round 12
// 407.195 us; speedup vs baseline: 1.0284x; 1.0119x over previous
//
#include <hip/hip_runtime.h>

#define N_NODES 10000
#define N_EDGES 160000
#define HD 512
#define EDD 16

typedef unsigned short u16;
typedef __attribute__((ext_vector_type(8))) short bf16x8;
typedef __attribute__((ext_vector_type(4))) float f32x4;
typedef unsigned int u32;

__device__ __forceinline__ float bf2f(u16 u){
  unsigned int x = ((unsigned int)u) << 16;
  return __builtin_bit_cast(float, x);
}
__device__ __forceinline__ u16 f2bf(float f){
  unsigned int x = __builtin_bit_cast(unsigned int, f);
  unsigned int r = (x + 0x7fffu + ((x >> 16) & 1u)) >> 16;
  return (u16)r;
}
// dtype-flagged scalar load/store: flag!=0 -> f32, else bf16
__device__ __forceinline__ float ldx(const void* p, long long i, int f32){
  return f32 ? ((const float*)p)[i] : bf2f(((const u16*)p)[i]);
}
__device__ __forceinline__ void stx(void* p, long long i, int f32, float v){
  if (f32) ((float*)p)[i] = v; else ((u16*)p)[i] = f2bf(v);
}
// tanh-form gelu, NaN-free sigmoid form: x * rcp(1 + e^{-a})
__device__ __forceinline__ float gelu_f(float x){
  float c = x * x;
  float a = x * (1.5957691216f + 0.0713548162f * c);
  float e = __expf(-a);
  return x * __builtin_amdgcn_rcpf(1.0f + e);
}
__device__ __forceinline__ f32x4 mfma16(bf16x8 a, bf16x8 b, f32x4 c){
  return __builtin_amdgcn_mfma_f32_16x16x32_bf16(a, b, c, 0, 0, 0);
}
// LDS slot swizzle for [row][32]-u16 tiles (4 x 16B slots per row)
__device__ __forceinline__ int swz8(int row, int slot){
  return (slot ^ ((row >> 1) & 3)) * 8;
}
// load 8 contiguous elems as bf16x8 from f32-or-bf16 source (8-elem aligned)
__device__ __forceinline__ bf16x8 ld8(const void* p, long long i, int f32){
  if (!f32) return *(const bf16x8*)((const u16*)p + i);
  const float* q = (const float*)p + i;
  float4 a = *(const float4*)q, b = *(const float4*)(q + 4);
  u16 t[8] = { f2bf(a.x), f2bf(a.y), f2bf(a.z), f2bf(a.w),
               f2bf(b.x), f2bf(b.y), f2bf(b.z), f2bf(b.w) };
  return *(const bf16x8*)t;
}
__device__ __forceinline__ void stage8(const void* src, long long idx, int f32, u16* dst){
  bf16x8 v = ld8(src, idx, f32);
  *(bf16x8*)dst = v;
}

// ---------------- dtype probe
__device__ __forceinline__ int probe_rand(const void* p, int l){
  const u16* q = (const u16*)p;
  float mx = 0.f;
  #pragma unroll
  for (int i = 0; i < 4; ++i) mx = fmaxf(mx, fabsf(bf2f(q[l * 4 + i])));
  #pragma unroll
  for (int m = 1; m < 64; m <<= 1) mx = fmaxf(mx, __shfl_xor(mx, m, 64));
  return (mx > 1e3f) ? 1 : 0;
}
// F[0]=h F[1]=ea F[2]=msg_w1 F[3]=msg_w2 F[4]=upd_w1 F[5]=upd_w2
// F[6]=em_w1 F[7]=em_w2 F[8]=eg_w F[9]=norm_g F[10]=en_g F[11]=out(=h)
__global__ __launch_bounds__(64) void kprobe(
    const void* h, const void* ea, const void* mw1, const void* mw2,
    const void* uw1, const void* uw2, const void* ew1, const void* ew2,
    const void* egw, const void* ng, const void* eng, int* F)
{
  const int l = threadIdx.x;
  int f0 = probe_rand(h, l),   f1 = probe_rand(ea, l),  f2 = probe_rand(mw1, l);
  int f3 = probe_rand(mw2, l), f4 = probe_rand(uw1, l), f5 = probe_rand(uw2, l);
  int f6 = probe_rand(ew1, l), f7 = probe_rand(ew2, l), f8 = probe_rand(egw, l);
  if (l == 0){
    F[0] = f0; F[1] = f1; F[2] = f2; F[3] = f3; F[4] = f4; F[5] = f5;
    F[6] = f6; F[7] = f7; F[8] = f8;
    F[9]  = (((const u16*)ng)[0]  == 0) ? 1 : 0;
    F[10] = (((const u16*)eng)[0] == 0) ? 1 : 0;
    F[11] = f0;
  }
}

__global__ void kfill(u16* __restrict__ out, long long n, float val){
  long long i = (long long)blockIdx.x * 256 + threadIdx.x;
  if (i < n) out[i] = f2bf(val);
}

// ---------------- fused prep #1, grid 2684:
// [0,2500): hB convert  [2500,2572): W1T 64x64 LDS-tiled transpose
// [2572,2668): WceT build  [2668,2684): bfused (j-parallel x8, 32 n/block)
__global__ __launch_bounds__(256) void kprep(
    const void* __restrict__ h, const void* __restrict__ mw1,
    const void* __restrict__ ew1, const void* __restrict__ egw,
    const void* __restrict__ mb2, const void* __restrict__ uw1,
    const int* __restrict__ F,
    u16* __restrict__ hB, u16* __restrict__ W1T, u16* __restrict__ WceT,
    float* __restrict__ bfused)
{
  __shared__ float tl[64][65];
  const int b = blockIdx.x, tid = threadIdx.x;
  if (b < 2500){
    const long long i = ((long long)b * 256 + tid) * 8;
    if (i < (long long)N_NODES * HD)
      *(bf16x8*)(hB + i) = ld8(h, i, F[0]);
  } else if (b < 2572){
    // W1T[n][k] = (k<528) ? msg_w1[k][n] : 0 ; K=528->Kpad 544, N=512
    const int b2 = b - 2500;
    const int kt0 = (b2 >> 3) * 64, nt0 = (b2 & 7) * 64;
    const int ty = tid >> 6, tx = tid & 63;
    const int fw = F[2];
    #pragma unroll
    for (int q = 0; q < 16; ++q){
      const int r = ty * 16 + q;
      const int sr = kt0 + r;
      tl[r][tx] = (sr < 528) ? ldx(mw1, (long long)sr * 512 + nt0 + tx, fw) : 0.f;
    }
    __syncthreads();
    #pragma unroll
    for (int q = 0; q < 16; ++q){
      const int r = ty * 16 + q;
      const int k = kt0 + tx;
      if (k < 544) W1T[(size_t)(nt0 + r) * 544 + k] = f2bf(tl[tx][r]);
    }
  } else if (b < 2668){
    const int i = (b - 2572) * 256 + tid;
    const int c = i >> 9, k = i & 511;
    float v = 0.f;
    if (c < 16)       v = ldx(ew1, (long long)k * 16 + c, F[6]);
    else if (c < 32)  v = ldx(ew1, (long long)(512 + k) * 16 + (c - 16), F[6]);
    else if (c == 32) v = ldx(egw, k, F[8]);
    else if (c == 33) v = ldx(egw, 512 + k, F[8]);
    WceT[i] = f2bf(v);
  } else {
    // bfused[n] = sum_j msg_b2[j]*upd_w1[512+j][n]; 16 blocks x 32 n,
    // 8-way j-parallel per block (64-iter loop, coalesced row slices)
    float* ls   = &tl[0][0];          // 512 floats (b2 staged)
    float* part = &tl[0][0] + 1024;   // 8 x 33 partials
    const int f3 = F[3], f4 = F[4];
    for (int j = tid; j < 512; j += 256) ls[j] = ldx(mb2, j, f3);
    __syncthreads();
    const int nn = tid & 31, jg = tid >> 5;
    const int n = (b - 2668) * 32 + nn;
    float a = 0.f;
    for (int jj = 0; jj < 64; ++jj){
      const int j = jg * 64 + jj;
      a += ls[j] * ldx(uw1, (long long)(512 + j) * 512 + n, f4);
    }
    part[jg * 33 + nn] = a;
    __syncthreads();
    if (jg == 0){
      float s = a;
      #pragma unroll
      for (int g = 1; g < 8; ++g) s += part[g * 33 + nn];
      bfused[n] = s;
    }
  }
}

// ---------------- fused prep #2 (after kedge2 frees PE/WceT), grid 192:
// [0,128): WU1T tiled transpose (1024x512 -> [512][1024])
// [128,192): WU2T tiled transpose (512x512 -> [512][512])
__global__ __launch_bounds__(256) void kprep2(
    const void* __restrict__ uw1, const void* __restrict__ uw2,
    const int* __restrict__ F, u16* __restrict__ WU1T, u16* __restrict__ WU2T)
{
  __shared__ float tl[64][65];
  const int b = blockIdx.x, tid = threadIdx.x;
  const int ty = tid >> 6, tx = tid & 63;
  if (b < 128){
    const int kt0 = (b >> 3) * 64, nt0 = (b & 7) * 64;
    const int fw = F[4];
    #pragma unroll
    for (int q = 0; q < 16; ++q){
      const int r = ty * 16 + q;
      tl[r][tx] = ldx(uw1, (long long)(kt0 + r) * 512 + nt0 + tx, fw);
    }
    __syncthreads();
    #pragma unroll
    for (int q = 0; q < 16; ++q){
      const int r = ty * 16 + q;
      WU1T[(size_t)(nt0 + r) * 1024 + kt0 + tx] = f2bf(tl[tx][r]);
    }
  } else {
    const int b2 = b - 128;
    const int kt0 = (b2 >> 3) * 64, nt0 = (b2 & 7) * 64;
    const int fw = F[5];
    #pragma unroll
    for (int q = 0; q < 16; ++q){
      const int r = ty * 16 + q;
      tl[r][tx] = ldx(uw2, (long long)(kt0 + r) * 512 + nt0 + tx, fw);
    }
    __syncthreads();
    #pragma unroll
    for (int q = 0; q < 16; ++q){
      const int r = ty * 16 + q;
      WU2T[(size_t)(nt0 + r) * 512 + kt0 + tx] = f2bf(tl[tx][r]);
    }
  }
}

__global__ void kdeg(const int* __restrict__ dst, int* __restrict__ deg){
  int e = blockIdx.x * 256 + threadIdx.x;
  if (e < N_EDGES) atomicAdd(&deg[dst[e]], 1);
}

// ---------------- exclusive scan of deg -> start
__global__ __launch_bounds__(256) void kscan(const int* __restrict__ deg,
                                             int* __restrict__ start){
  __shared__ int ls[256];
  const int t = threadIdx.x;
  const int base = t * 40;
  int s = 0;
  for (int i = 0; i < 40; ++i){ int idx = base + i; if (idx < N_NODES) s += deg[idx]; }
  ls[t] = s; __syncthreads();
  for (int off = 1; off < 256; off <<= 1){
    int v = (t >= off) ? ls[t - off] : 0;
    __syncthreads();
    ls[t] += v;
    __syncthreads();
  }
  int run = (t == 0) ? 0 : ls[t - 1];
  for (int i = 0; i < 40; ++i){
    int idx = base + i;
    if (idx < N_NODES){ start[idx] = run; run += deg[idx]; }
  }
}

// ---------------- counting-sort scatter: edges sorted by dst
__global__ void kscatter(const int* __restrict__ srcI, const int* __restrict__ dstI,
                         const int* __restrict__ start, int* __restrict__ cursor,
                         int* __restrict__ sSrc, int* __restrict__ sDst,
                         int* __restrict__ sIdx){
  int e = blockIdx.x * 256 + threadIdx.x;
  if (e < N_EDGES){
    int d = dstI[e];
    int p = start[d] + atomicAdd(&cursor[d], 1);
    sSrc[p] = srcI[e]; sDst[p] = d; sIdx[p] = e;
  }
}

// ---------------- fused: P = bf16(h @ msg_w1[:512] + b1) (x<8, BM128 BN64)
//                  and PE = bf16(h @ WceT^T) [N][48]     (x==8)
// grid (9,79): same-row-panel blocks adjacent in dispatch -> hB L2 reuse
__global__ __launch_bounds__(256, 4) void kprePE(
    const u16* __restrict__ hB, const u16* __restrict__ W1T,
    const void* __restrict__ msg_b1, const u16* __restrict__ WceT,
    const int* __restrict__ F, u16* __restrict__ P, u16* __restrict__ PE)
{
  __shared__ u16 As[128 * 32];
  __shared__ u16 Bs[64 * 32];
  const int tid = threadIdx.x;
  const int row0 = blockIdx.y * 128;
  const int w = tid >> 6, l = tid & 63;
  const int lm = l & 15, lk = l >> 4;
  if (blockIdx.x < 8){
    const int fw = F[2];
    const int n0 = blockIdx.x * 64;
    f32x4 acc[2][4];
    f32x4 z4 = {0.f, 0.f, 0.f, 0.f};
    #pragma unroll
    for (int i = 0; i < 2; ++i)
      #pragma unroll
      for (int j = 0; j < 4; ++j) acc[i][j] = z4;
    const int nB = tid >> 2, kqB = tid & 3;
    for (int kt = 0; kt < 16; ++kt){
      const int kk = kt * 32;
      #pragma unroll
      for (int i = 0; i < 2; ++i){
        int t = tid + i * 256;
        int m = t >> 2, kq = t & 3;
        int gr = row0 + m; if (gr > N_NODES - 1) gr = N_NODES - 1;
        *(uint4*)&As[m * 32 + swz8(m, kq)] = *(const uint4*)(hB + (size_t)gr * HD + kk + kq * 8);
      }
      *(uint4*)&Bs[nB * 32 + swz8(nB, kqB)] =
          *(const uint4*)(W1T + (size_t)(n0 + nB) * 544 + kk + kqB * 8);
      __syncthreads();
      bf16x8 af[2], bfv[4];
      #pragma unroll
      for (int i = 0; i < 2; ++i){
        const int R = w * 32 + i * 16 + lm;
        af[i] = *(const bf16x8*)&As[R * 32 + swz8(R, lk)];
      }
      #pragma unroll
      for (int j = 0; j < 4; ++j){
        const int R = j * 16 + lm;
        bfv[j] = *(const bf16x8*)&Bs[R * 32 + swz8(R, lk)];
      }
      #pragma unroll
      for (int i = 0; i < 2; ++i)
        #pragma unroll
        for (int j = 0; j < 4; ++j)
          acc[i][j] = mfma16(af[i], bfv[j], acc[i][j]);
      __syncthreads();
    }
    #pragma unroll
    for (int j = 0; j < 4; ++j){
      const int col = n0 + j * 16 + lm;
      const float bias = ldx(msg_b1, col, fw);
      #pragma unroll
      for (int i = 0; i < 2; ++i){
        const int rb = row0 + w * 32 + i * 16 + lk * 4;
        #pragma unroll
        for (int r = 0; r < 4; ++r){
          int gr = rb + r;
          if (gr < N_NODES)
            P[(size_t)gr * HD + col] = f2bf(acc[i][j][r] + bias);
        }
      }
    }
  } else {
    f32x4 acc[2][3];
    f32x4 z4 = {0.f, 0.f, 0.f, 0.f};
    #pragma unroll
    for (int i = 0; i < 2; ++i)
      #pragma unroll
      for (int j = 0; j < 3; ++j) acc[i][j] = z4;
    for (int kt = 0; kt < 16; ++kt){
      const int kk = kt * 32;
      #pragma unroll
      for (int i = 0; i < 2; ++i){
        int t = tid + i * 256;
        int m = t >> 2, kq = t & 3;
        int gr = row0 + m; if (gr > N_NODES - 1) gr = N_NODES - 1;
        *(uint4*)&As[m * 32 + swz8(m, kq)] = *(const uint4*)(hB + (size_t)gr * HD + kk + kq * 8);
      }
      if (tid < 192){
        int c = tid >> 2, kq = tid & 3;
        *(uint4*)&Bs[c * 32 + swz8(c, kq)] =
            *(const uint4*)(WceT + (size_t)c * 512 + kk + kq * 8);
      }
      __syncthreads();
      bf16x8 af[2], bfv[3];
      #pragma unroll
      for (int i = 0; i < 2; ++i){
        const int R = w * 32 + i * 16 + lm;
        af[i] = *(const bf16x8*)&As[R * 32 + swz8(R, lk)];
      }
      #pragma unroll
      for (int j = 0; j < 3; ++j){
        const int R = j * 16 + lm;
        bfv[j] = *(const bf16x8*)&Bs[R * 32 + swz8(R, lk)];
      }
      #pragma unroll
      for (int i = 0; i < 2; ++i)
        #pragma unroll
        for (int j = 0; j < 3; ++j)
          acc[i][j] = mfma16(af[i], bfv[j], acc[i][j]);
      __syncthreads();
    }
    #pragma unroll
    for (int j = 0; j < 3; ++j){
      const int col = j * 16 + lm;
      #pragma unroll
      for (int i = 0; i < 2; ++i){
        const int rb = row0 + w * 32 + i * 16 + lk * 4;
        #pragma unroll
        for (int r = 0; r < 4; ++r){
          int gr = rb + r;
          if (gr < N_NODES)
            PE[(size_t)gr * 48 + col] = f2bf(acc[i][j][r]);
        }
      }
    }
  }
}

// ---------------- edge update, decomposed: 1 thread = 1 edge, grid 625
__global__ __launch_bounds__(256) void kedge2(
    const void* __restrict__ ea, const u16* __restrict__ PE,
    const void* __restrict__ em_w1, const void* __restrict__ em_w2,
    const void* __restrict__ em_b1, const void* __restrict__ em_b2,
    const void* __restrict__ eg_w, const void* __restrict__ eg_b,
    const void* __restrict__ en_g, const void* __restrict__ en_b,
    const int* __restrict__ F,
    const int* __restrict__ srcI, const int* __restrict__ dstI,
    void* __restrict__ dout)
{
  __shared__ float wt[16][17];
  __shared__ float w2s[256];
  __shared__ float egt[16], b1e[16], b2s[16], gns[16], bns[16];
  __shared__ float egb_s;
  const int tid = threadIdx.x;
  const int fea = F[1], fem1 = F[6], fem2 = F[7], feg = F[8];
  const int fen = F[10], fo = F[11];
  { int k = tid >> 4, j = tid & 15;
    wt[k][j] = ldx(em_w1, (long long)(1024 + k) * 16 + j, fem1); }
  w2s[tid] = ldx(em_w2, tid, fem2);
  if (tid < 16){
    egt[tid] = ldx(eg_w, 1024 + tid, feg);
    b1e[tid] = ldx(em_b1, tid, fem1);
    b2s[tid] = ldx(em_b2, tid, fem2);
    gns[tid] = ldx(en_g, tid, fen);
    bns[tid] = ldx(en_b, tid, fen);
  }
  if (tid == 0) egb_s = ldx(eg_b, 0, feg);
  __syncthreads();

  const int e = blockIdx.x * 256 + tid;
  const int s = srcI[e], d = dstI[e];
  float earr[16];
  if (fea){
    const float4* q = (const float4*)((const float*)ea + (size_t)e * 16);
    float4 v0 = q[0], v1 = q[1], v2 = q[2], v3 = q[3];
    earr[0]=v0.x; earr[1]=v0.y; earr[2]=v0.z; earr[3]=v0.w;
    earr[4]=v1.x; earr[5]=v1.y; earr[6]=v1.z; earr[7]=v1.w;
    earr[8]=v2.x; earr[9]=v2.y; earr[10]=v2.z; earr[11]=v2.w;
    earr[12]=v3.x; earr[13]=v3.y; earr[14]=v3.z; earr[15]=v3.w;
  } else {
    const u16* q = (const u16*)ea + (size_t)e * 16;
    bf16x8 a = *(const bf16x8*)q, b = *(const bf16x8*)(q + 8);
    #pragma unroll
    for (int j = 0; j < 8; ++j){ earr[j] = bf2f((u16)a[j]); earr[8 + j] = bf2f((u16)b[j]); }
  }
  const u16* prs = PE + (size_t)s * 48;
  const u16* prd = PE + (size_t)d * 48;
  bf16x8 ps0 = *(const bf16x8*)prs,        ps1 = *(const bf16x8*)(prs + 8);
  bf16x8 pd0 = *(const bf16x8*)(prd + 16), pd1 = *(const bf16x8*)(prd + 24);
  const float gs = bf2f(prs[32]), gd = bf2f(prd[33]);
  float t[16];
  #pragma unroll
  for (int j = 0; j < 8; ++j){
    t[j]     = bf2f((u16)ps0[j]) + bf2f((u16)pd0[j]) + b1e[j];
    t[8 + j] = bf2f((u16)ps1[j]) + bf2f((u16)pd1[j]) + b1e[8 + j];
  }
  float gl = gs + gd + egb_s;
  #pragma unroll
  for (int k = 0; k < 16; ++k){
    const float ek = earr[k];
    gl += ek * egt[k];
    #pragma unroll
    for (int j = 0; j < 16; ++j) t[j] += ek * wt[k][j];
  }
  const float gate = __builtin_amdgcn_rcpf(1.0f + __expf(-gl));
  float gj[16];
  #pragma unroll
  for (int j = 0; j < 16; ++j) gj[j] = gelu_f(t[j]);
  float rv[16]; float s1 = 0.f, s2 = 0.f;
  #pragma unroll
  for (int j = 0; j < 16; ++j){
    float dlt = b2s[j];
    #pragma unroll
    for (int k = 0; k < 16; ++k) dlt += gj[k] * w2s[k * 16 + j];
    rv[j] = earr[j] + 0.1f * gate * dlt;
    s1 += rv[j]; s2 += rv[j] * rv[j];
  }
  const float mu  = s1 * (1.f / 16.f);
  const float var = s2 * (1.f / 16.f) - mu * mu;
  const float inv = rsqrtf(var + 1e-5f);
  if (fo){
    float* ob = (float*)dout + (size_t)N_NODES * HD + (size_t)e * 16;
    #pragma unroll
    for (int j = 0; j < 16; ++j) ob[j] = (rv[j] - mu) * inv * gns[j] + bns[j];
  } else {
    u16 tmp[16];
    #pragma unroll
    for (int j = 0; j < 16; ++j) tmp[j] = f2bf((rv[j] - mu) * inv * gns[j] + bns[j]);
    u16* ob = (u16*)dout + (size_t)N_NODES * HD + (size_t)e * 16;
    *(uint4*)ob = *(uint4*)&tmp[0];
    *(uint4*)(ob + 8) = *(uint4*)&tmp[8];
  }
}

// ---------------- WfT[n][k] = sum_j WU1T[n][512+j] * msg_w2[k][j]
// grid (8,4): x=colblock, y=rowblock
__global__ __launch_bounds__(256, 4) void kWf(
    const u16* __restrict__ WU1T, const void* __restrict__ mw2,
    const int* __restrict__ F, u16* __restrict__ WfT)
{
  __shared__ u16 As[128 * 32];
  __shared__ u16 Bs[64 * 32];
  const int tid = threadIdx.x;
  const int f3 = F[3];
  const int row0 = blockIdx.y * 128, n0 = blockIdx.x * 64;
  f32x4 acc[2][4];
  f32x4 z4 = {0.f, 0.f, 0.f, 0.f};
  #pragma unroll
  for (int i = 0; i < 2; ++i)
    #pragma unroll
    for (int j = 0; j < 4; ++j) acc[i][j] = z4;
  const int w = tid >> 6, l = tid & 63;
  const int lm = l & 15, lk = l >> 4;
  const int nB = tid >> 2, kqB = tid & 3;
  for (int kt = 0; kt < 16; ++kt){
    const int kk = kt * 32;
    #pragma unroll
    for (int i = 0; i < 2; ++i){
      int t = tid + i * 256;
      int m = t >> 2, kq = t & 3;
      *(uint4*)&As[m * 32 + swz8(m, kq)] =
          *(const uint4*)(WU1T + (size_t)(row0 + m) * 1024 + 512 + kk + kq * 8);
    }
    stage8(mw2, (long long)(n0 + nB) * 512 + kk + kqB * 8, f3,
           &Bs[nB * 32 + swz8(nB, kqB)]);
    __syncthreads();
    bf16x8 af[2], bfv[4];
    #pragma unroll
    for (int i = 0; i < 2; ++i){
      const int R = w * 32 + i * 16 + lm;
      af[i] = *(const bf16x8*)&As[R * 32 + swz8(R, lk)];
    }
    #pragma unroll
    for (int j = 0; j < 4; ++j){
      const int R = j * 16 + lm;
      bfv[j] = *(const bf16x8*)&Bs[R * 32 + swz8(R, lk)];
    }
    #pragma unroll
    for (int i = 0; i < 2; ++i)
      #pragma unroll
      for (int j = 0; j < 4; ++j)
        acc[i][j] = mfma16(af[i], bfv[j], acc[i][j]);
    __syncthreads();
  }
  #pragma unroll
  for (int j = 0; j < 4; ++j){
    const int col = n0 + j * 16 + lm;
    #pragma unroll
    for (int i = 0; i < 2; ++i){
      const int rb = row0 + w * 32 + i * 16 + lk * 4;
      #pragma unroll
      for (int r = 0; r < 4; ++r)
        WfT[(size_t)(rb + r) * 512 + col] = f2bf(acc[i][j][r]);
    }
  }
}

// ---------------- message via single K=32 MFMA tile + pipelined P-gather +
// segmented reduce. P loads for iteration j+1 issued before j's Sf writes,
// hiding L2 latency under the Sf+barrier+reduce phase of iteration j.
__global__ __launch_bounds__(256, 4) void kmsg4(
    const u16* __restrict__ P, const void* __restrict__ dout,
    const u16* __restrict__ W1T, const int* __restrict__ F,
    const int* __restrict__ sSrc, const int* __restrict__ sDst,
    const int* __restrict__ sIdx,
    float* __restrict__ agg)
{
  __shared__ __align__(16) float SMEM[4352];
  u16*   As = (u16*)SMEM;
  u16*   Bs = (u16*)SMEM + 4096;
  float* Sf = SMEM;
  __shared__ int src_s[128];
  __shared__ int dst_s[128];
  const int tid = threadIdx.x;
  const int fo = F[11];
  const void* e_base = fo ? (const void*)((const float*)dout + (size_t)N_NODES * HD)
                          : (const void*)((const u16*)dout + (size_t)N_NODES * HD);
  const int row0 = blockIdx.x * 128, n0 = blockIdx.y * 128;
  if (tid < 128){
    src_s[tid] = sSrc[row0 + tid];
    dst_s[tid] = sDst[row0 + tid];
  }
  #pragma unroll
  for (int i = 0; i < 2; ++i){
    int t = tid + i * 256;
    int m = t >> 2, kq = t & 3;
    if (kq < 2){
      const long long ie = sIdx[row0 + m];
      stage8(e_base, ie * EDD + kq * 8, fo, &As[m * 32 + swz8(m, kq)]);
      *(uint4*)&Bs[m * 32 + swz8(m, kq)] =
          *(const uint4*)(W1T + (size_t)(n0 + m) * 544 + 512 + kq * 8);
    } else {
      uint4 z = {0,0,0,0};
      *(uint4*)&As[m * 32 + swz8(m, kq)] = z;
      *(uint4*)&Bs[m * 32 + swz8(m, kq)] = z;
    }
  }
  __syncthreads();
  const int w = tid >> 6, l = tid & 63;
  const int wr = w >> 1, wc = w & 1, lm = l & 15, lk = l >> 4;
  f32x4 acc[4][4];
  bf16x8 af[4], bfv[4];
  #pragma unroll
  for (int i = 0; i < 4; ++i){
    const int R = wr * 64 + i * 16 + lm;
    af[i] = *(const bf16x8*)&As[R * 32 + swz8(R, lk)];
  }
  #pragma unroll
  for (int j = 0; j < 4; ++j){
    const int R = wc * 64 + j * 16 + lm;
    bfv[j] = *(const bf16x8*)&Bs[R * 32 + swz8(R, lk)];
  }
  f32x4 z4 = {0.f, 0.f, 0.f, 0.f};
  #pragma unroll
  for (int i = 0; i < 4; ++i)
    #pragma unroll
    for (int j = 0; j < 4; ++j)
      acc[i][j] = mfma16(af[i], bfv[j], z4);
  u32 poff[4][4];
  #pragma unroll
  for (int i = 0; i < 4; ++i)
    #pragma unroll
    for (int r = 0; r < 4; ++r)
      poff[i][r] = (u32)src_s[wr * 64 + i * 16 + lk * 4 + r] * HD;
  // prefetch j=0's 16 P gathers (latency overlaps index build + barrier)
  float pv[4][16];
  {
    const int col0 = n0 + wc * 64 + lm;
    #pragma unroll
    for (int q = 0; q < 16; ++q)
      pv[0][q] = bf2f(P[poff[q >> 2][q & 3] + col0]);
  }
  const int cj = tid & 31, chunk = tid >> 5;
  const int rbase = chunk * 16;
  u32 aoff[16]; unsigned maskb = 0;
  {
    int dprev = dst_s[rbase];
    aoff[0] = (u32)dprev * HD;
    #pragma unroll
    for (int rr = 1; rr < 16; ++rr){
      const int dn = dst_s[rbase + rr];
      if (dn == dprev) maskb |= (1u << rr);
      aoff[rr] = (u32)dn * HD;
      dprev = dn;
    }
  }
  __syncthreads();
  const int sfb = wc * 16 + lm;
  #pragma unroll
  for (int j = 0; j < 4; ++j){
    // issue next j's gathers early; results consumed after barrier+reduce
    if (j < 3){
      const int coln = n0 + wc * 64 + (j + 1) * 16 + lm;
      #pragma unroll
      for (int q = 0; q < 16; ++q)
        pv[j + 1][q] = bf2f(P[poff[q >> 2][q & 3] + coln]);
    }
    #pragma unroll
    for (int i = 0; i < 4; ++i)
      #pragma unroll
      for (int r = 0; r < 4; ++r){
        const int row = wr * 64 + i * 16 + lk * 4 + r;
        Sf[row * 34 + sfb] = gelu_f(acc[i][j][r] + pv[j][i * 4 + r]);
      }
    __syncthreads();
    const int acol = n0 + (cj >> 4) * 64 + j * 16 + (cj & 15);
    float run = Sf[rbase * 34 + cj];
    #pragma unroll
    for (int rr = 1; rr < 16; ++rr){
      const float v = Sf[(rbase + rr) * 34 + cj];
      if (maskb & (1u << rr)) run += v;
      else { atomicAdd(&agg[(size_t)aoff[rr - 1] + acol], run); run = v; }
    }
    atomicAdd(&agg[(size_t)aoff[15] + acol], run);
    __syncthreads();
  }
}

// ---------------- U = bf16(gelu(h@W1u_top + S@Wf + deg*bfused + b1u))
// grid (8,79): x=colblock (BN=64), y=rowblock (BM=128), K=1024
__global__ __launch_bounds__(256, 4) void kupd1f(
    const u16* __restrict__ hB, const float* __restrict__ S,
    const u16* __restrict__ WU1T, const u16* __restrict__ WfT,
    const void* __restrict__ upd_b1, const float* __restrict__ bfused,
    const int* __restrict__ deg, const int* __restrict__ F,
    u16* __restrict__ U)
{
  __shared__ u16 As[128 * 32];
  __shared__ u16 Bs[64 * 32];
  const int tid = threadIdx.x;
  const int fw = F[4];
  const int row0 = blockIdx.y * 128, n0 = blockIdx.x * 64;
  f32x4 acc[2][4];
  f32x4 z4 = {0.f, 0.f, 0.f, 0.f};
  #pragma unroll
  for (int i = 0; i < 2; ++i)
    #pragma unroll
    for (int j = 0; j < 4; ++j) acc[i][j] = z4;
  const int w = tid >> 6, l = tid & 63;
  const int lm = l & 15, lk = l >> 4;
  const int nB = tid >> 2, kqB = tid & 3;
  const int am = tid >> 1, ah = tid & 1;
  const int agr = row0 + am;
  for (int kt = 0; kt < 32; ++kt){
    const int kk = kt * 32;
    if (kk < 512){
      #pragma unroll
      for (int i = 0; i < 2; ++i){
        int t = tid + i * 256;
        int m = t >> 2, kq = t & 3;
        int gr = row0 + m; if (gr > N_NODES - 1) gr = N_NODES - 1;
        *(uint4*)&As[m * 32 + swz8(m, kq)] = *(const uint4*)(hB + (size_t)gr * HD + kk + kq * 8);
      }
      *(uint4*)&Bs[nB * 32 + swz8(nB, kqB)] =
          *(const uint4*)(WU1T + (size_t)(n0 + nB) * 1024 + kk + kqB * 8);
    } else {
      const int ks = kk - 512;
      u16 tmp[16];
      if (agr < N_NODES){
        const float4* sp = (const float4*)(S + (size_t)agr * HD + ks + ah * 16);
        #pragma unroll
        for (int q = 0; q < 4; ++q){
          float4 v = sp[q];
          tmp[q*4+0] = f2bf(v.x); tmp[q*4+1] = f2bf(v.y);
          tmp[q*4+2] = f2bf(v.z); tmp[q*4+3] = f2bf(v.w);
        }
      } else {
        #pragma unroll
        for (int q = 0; q < 16; ++q) tmp[q] = 0;
      }
      *(uint4*)&As[am * 32 + swz8(am, ah * 2)]     = *(uint4*)&tmp[0];
      *(uint4*)&As[am * 32 + swz8(am, ah * 2 + 1)] = *(uint4*)&tmp[8];
      *(uint4*)&Bs[nB * 32 + swz8(nB, kqB)] =
          *(const uint4*)(WfT + (size_t)(n0 + nB) * 512 + ks + kqB * 8);
    }
    __syncthreads();
    bf16x8 af[2], bfv[4];
    #pragma unroll
    for (int i = 0; i < 2; ++i){
      const int R = w * 32 + i * 16 + lm;
      af[i] = *(const bf16x8*)&As[R * 32 + swz8(R, lk)];
    }
    #pragma unroll
    for (int j = 0; j < 4; ++j){
      const int R = j * 16 + lm;
      bfv[j] = *(const bf16x8*)&Bs[R * 32 + swz8(R, lk)];
    }
    #pragma unroll
    for (int i = 0; i < 2; ++i)
      #pragma unroll
      for (int j = 0; j < 4; ++j)
        acc[i][j] = mfma16(af[i], bfv[j], acc[i][j]);
    __syncthreads();
  }
  #pragma unroll
  for (int j = 0; j < 4; ++j){
    const int col = n0 + j * 16 + lm;
    const float bias = ldx(upd_b1, col, fw);
    const float bfv2 = bfused[col];
    #pragma unroll
    for (int i = 0; i < 2; ++i){
      const int rb = row0 + w * 32 + i * 16 + lk * 4;
      #pragma unroll
      for (int r = 0; r < 4; ++r){
        int gr = rb + r;
        if (gr < N_NODES)
          U[(size_t)gr * HD + col] =
              f2bf(gelu_f(acc[i][j][r] + bias + (float)deg[gr] * bfv2));
      }
    }
  }
}

// ---------------- h2b = bf16(U @ upd_w2 + b2)   grid (8,79), K=512
__global__ __launch_bounds__(256, 4) void kupd2(
    const u16* __restrict__ U, const u16* __restrict__ WU2T,
    const void* __restrict__ upd_b2, const int* __restrict__ F,
    u16* __restrict__ h2b)
{
  __shared__ u16 As[128 * 32];
  __shared__ u16 Bs[64 * 32];
  const int tid = threadIdx.x;
  const int fw = F[5];
  const int row0 = blockIdx.y * 128, n0 = blockIdx.x * 64;
  f32x4 acc[2][4];
  f32x4 z4 = {0.f, 0.f, 0.f, 0.f};
  #pragma unroll
  for (int i = 0; i < 2; ++i)
    #pragma unroll
    for (int j = 0; j < 4; ++j) acc[i][j] = z4;
  const int w = tid >> 6, l = tid & 63;
  const int lm = l & 15, lk = l >> 4;
  const int nB = tid >> 2, kqB = tid & 3;
  for (int kt = 0; kt < 16; ++kt){
    const int kk = kt * 32;
    #pragma unroll
    for (int i = 0; i < 2; ++i){
      int t = tid + i * 256;
      int m = t >> 2, kq = t & 3;
      int gr = row0 + m; if (gr > N_NODES - 1) gr = N_NODES - 1;
      *(uint4*)&As[m * 32 + swz8(m, kq)] = *(const uint4*)(U + (size_t)gr * HD + kk + kq * 8);
    }
    *(uint4*)&Bs[nB * 32 + swz8(nB, kqB)] =
        *(const uint4*)(WU2T + (size_t)(n0 + nB) * 512 + kk + kqB * 8);
    __syncthreads();
    bf16x8 af[2], bfv[4];
    #pragma unroll
    for (int i = 0; i < 2; ++i){
      const int R = w * 32 + i * 16 + lm;
      af[i] = *(const bf16x8*)&As[R * 32 + swz8(R, lk)];
    }
    #pragma unroll
    for (int j = 0; j < 4; ++j){
      const int R = j * 16 + lm;
      bfv[j] = *(const bf16x8*)&Bs[R * 32 + swz8(R, lk)];
    }
    #pragma unroll
    for (int i = 0; i < 2; ++i)
      #pragma unroll
      for (int j = 0; j < 4; ++j)
        acc[i][j] = mfma16(af[i], bfv[j], acc[i][j]);
    __syncthreads();
  }
  #pragma unroll
  for (int j = 0; j < 4; ++j){
    const int col = n0 + j * 16 + lm;
    const float bias = ldx(upd_b2, col, fw);
    #pragma unroll
    for (int i = 0; i < 2; ++i){
      const int rb = row0 + w * 32 + i * 16 + lk * 4;
      #pragma unroll
      for (int r = 0; r < 4; ++r){
        int gr = rb + r;
        if (gr < N_NODES)
          h2b[(size_t)gr * HD + col] = f2bf(acc[i][j][r] + bias);
      }
    }
  }
}

// ---------------- h_out = LN(h + h2)   grid 2500, 4 rows/block
__global__ __launch_bounds__(256) void kln(
    const void* __restrict__ h, const u16* __restrict__ h2b,
    const void* __restrict__ gg, const void* __restrict__ bbv,
    const int* __restrict__ F, void* __restrict__ dout)
{
  const int fh = F[0], fng = F[9], fo = F[11];
  const int w = threadIdx.x >> 6, l = threadIdx.x & 63;
  const int row = blockIdx.x * 4 + w;
  float x[8];
  #pragma unroll
  for (int j = 0; j < 8; ++j){
    const long long idx = (long long)row * HD + l * 8 + j;
    x[j] = ldx(h, idx, fh) + bf2f(h2b[idx]);
  }
  float s1 = 0.f, s2 = 0.f;
  #pragma unroll
  for (int j = 0; j < 8; ++j){ s1 += x[j]; s2 += x[j] * x[j]; }
  #pragma unroll
  for (int m = 1; m < 64; m <<= 1){ s1 += __shfl_xor(s1, m, 64); s2 += __shfl_xor(s2, m, 64); }
  const float mu  = s1 * (1.f / 512.f);
  const float var = s2 * (1.f / 512.f) - mu * mu;
  const float inv = rsqrtf(var + 1e-5f);
  #pragma unroll
  for (int j = 0; j < 8; ++j){
    const float gf = ldx(gg,  l * 8 + j, fng);
    const float bf = ldx(bbv, l * 8 + j, fng);
    stx(dout, (long long)row * HD + l * 8 + j, fo, (x[j] - mu) * inv * gf + bf);
  }
}

// ---------------- workspace layout (bytes), total 35,448,064 (unchanged)
#define OFF_S     0u            // N*512 f32 (scatter accum; later h2b bf16)
#define OFF_DEG   20480000u     // N ints
#define OFF_CUR   20520000u     // N ints (sort cursors)
#define OFF_F     20560000u     // 16 ints
#define OFF_START 20560064u     // N ints
#define OFF_AGGM  20600064u     // N*512 bf16 (P, then U)
#define OFF_W1T   30840064u     // 512*544 bf16
#define OFF_W2T   31397120u     // 512*512 bf16 (WfT)
#define OFF_WU1T  31921408u     // 512*1024 bf16 (PE first)
#define OFF_WU2T  32969984u     // 512*512 bf16 (WceT first)
#define OFF_WET   33494272u     // bfused (512 f32)
#define OFF_SSRC  33528064u     // E ints
#define OFF_SDST  34168064u     // E ints
#define OFF_SIDX  34808064u     // E ints
#define WS_NEEDED 35448064u

extern "C" void kernel_launch(void* const* d_in, const int* in_sizes, int n_in,
                              void* d_out, int out_size, void* d_ws, size_t ws_size,
                              hipStream_t stream)
{
  const void* h      = d_in[0];
  const void* ea     = d_in[1];
  const void* msg_w1 = d_in[2];
  const void* msg_b1 = d_in[3];
  const void* msg_w2 = d_in[4];
  const void* msg_b2 = d_in[5];
  const void* upd_w1 = d_in[6];
  const void* upd_b1 = d_in[7];
  const void* upd_w2 = d_in[8];
  const void* upd_b2 = d_in[9];
  const void* norm_g = d_in[10];
  const void* norm_b = d_in[11];
  const void* em_w1  = d_in[12];
  const void* em_b1  = d_in[13];
  const void* em_w2  = d_in[14];
  const void* em_b2  = d_in[15];
  const void* eg_w   = d_in[16];
  const void* eg_b   = d_in[17];
  const void* en_g   = d_in[18];
  const void* en_b   = d_in[19];
  const int* eidx    = (const int*)d_in[20];
  const int* srcI = eidx;
  const int* dstI = eidx + N_EDGES;

  float sent = 0.f;
  if (ws_size < (size_t)WS_NEEDED)            sent = 1000.f;
  else if (n_in != 21)                        sent = 2000.f;
  else if (in_sizes[0]  != N_NODES * HD)      sent = 3000.f;
  else if (in_sizes[20] != 2 * N_EDGES)       sent = 4000.f;
  else if (out_size != N_NODES*HD + N_EDGES*EDD) sent = 5000.f;
  if (sent != 0.f){
    kfill<<<(out_size + 255)/256, 256, 0, stream>>>((u16*)d_out, out_size, sent);
    return;
  }

  char* ws = (char*)d_ws;
  float* S      = (float*)(ws + OFF_S);
  u16*   h2b    = (u16*)(ws + OFF_S);      // alias: after kupd1f consumed S
  int*   deg    = (int*)(ws + OFF_DEG);
  int*   cur    = (int*)(ws + OFF_CUR);
  int*   F      = (int*)(ws + OFF_F);
  int*   start  = (int*)(ws + OFF_START);
  u16*   P      = (u16*)(ws + OFF_AGGM);   // alias: P dead after kmsg4
  u16*   U      = (u16*)(ws + OFF_AGGM);
  u16*   W1T    = (u16*)(ws + OFF_W1T);
  u16*   WfT    = (u16*)(ws + OFF_W2T);
  u16*   PE     = (u16*)(ws + OFF_WU1T);   // alias: PE dead after kedge2
  u16*   WU1T   = (u16*)(ws + OFF_WU1T);
  u16*   WceT   = (u16*)(ws + OFF_WU2T);   // alias: WceT dead after kprePE
  u16*   WU2T   = (u16*)(ws + OFF_WU2T);
  float* bfused = (float*)(ws + OFF_WET);
  int*   sSrc   = (int*)(ws + OFF_SSRC);
  int*   sDst   = (int*)(ws + OFF_SDST);
  int*   sIdx   = (int*)(ws + OFF_SIDX);

  // hB (bf16 h) lives in d_out's h_out region (dead until kln rewrites it).
  u16* hB = (u16*)d_out;

  // zero S + deg + cursors in one memset (contiguous)
  hipMemsetAsync(S, 0, (size_t)OFF_F, stream);

  kprobe<<<1, 64, 0, stream>>>(h, ea, msg_w1, msg_w2, upd_w1, upd_w2,
                               em_w1, em_w2, eg_w, norm_g, en_g, F);

  // fused prep: hB convert + tiled W1T + WceT + j-parallel bfused
  kprep<<<2684, 256, 0, stream>>>(h, msg_w1, em_w1, eg_w, msg_b2, upd_w1, F,
                                  hB, W1T, WceT, bfused);

  kprePE<<<dim3(9, 79), 256, 0, stream>>>(hB, W1T, msg_b1, WceT, F, P, PE);

  kdeg<<<(N_EDGES + 255)/256, 256, 0, stream>>>(dstI, deg);
  kscan<<<1, 256, 0, stream>>>(deg, start);
  kscatter<<<(N_EDGES + 255)/256, 256, 0, stream>>>(srcI, dstI, start, cur,
                                                    sSrc, sDst, sIdx);

  kedge2<<<625, 256, 0, stream>>>(ea, PE, em_w1, em_w2, em_b1, em_b2, eg_w, eg_b,
                                  en_g, en_b, F, srcI, dstI, d_out);

  // PE/WceT dead -> tiled transposes of the update MLP, then Wf build
  kprep2<<<192, 256, 0, stream>>>(upd_w1, upd_w2, F, WU1T, WU2T);
  kWf<<<dim3(8, 4), 256, 0, stream>>>(WU1T, msg_w2, F, WfT);

  kmsg4<<<dim3(1250, 4), 256, 0, stream>>>(P, d_out, W1T, F,
                                           sSrc, sDst, sIdx, S);
  kupd1f<<<dim3(8, 79), 256, 0, stream>>>(hB, S, WU1T, WfT, upd_b1, bfused,
                                          deg, F, U);
  kupd2<<<dim3(8, 79), 256, 0, stream>>>(U, WU2T, upd_b2, F, h2b);
  kln<<<2500, 256, 0, stream>>>(h, h2b, norm_g, norm_b, F, d_out);
}